// Round 12
// baseline (595.398 us; speedup 1.0000x reference)
//
#include <hip/hip_runtime.h>
#include <hip/hip_bf16.h>

#define NB 8
#define NS 256
#define ND 512
#define NH 8
#define NDH 64
#define NFF 2048
#define NE 8
#define NV 32000
#define NRH 256
#define MAXV 2
#define NEGV (-1e9f)

typedef __attribute__((ext_vector_type(8))) short short8;
typedef __attribute__((ext_vector_type(4))) float f32x4;

__device__ __forceinline__ unsigned short f2bf(float x) {
  unsigned int u = __float_as_uint(x);
  u = (u + 0x7fffu + ((u >> 16) & 1u)) >> 16;
  return (unsigned short)u;
}

// async global->LDS, 16 bytes per lane; LDS dest is wave-uniform base + lane*16
__device__ __forceinline__ void gload16(const unsigned short* g, unsigned short* l) {
  __builtin_amdgcn_global_load_lds(
      (const __attribute__((address_space(1))) unsigned int*)g,
      (__attribute__((address_space(3))) unsigned int*)l, 16, 0, 0);
}

// 32-col-row staging swizzle (lmhead): lane -> chunk (l&3) ^ ((l>>3)&3)
__device__ __forceinline__ int swzc(int lane) {
  return (lane & 3) ^ ((lane >> 3) & 3);
}

// ---------------- fused: weight casts + state init + embedding ----------------
__device__ __forceinline__ void cast8(const float* s, unsigned short* d, int j) {
  const float4* s4 = (const float4*)s;
  float4 a = s4[j * 2], b = s4[j * 2 + 1];
  short8 v;
  v[0] = (short)f2bf(a.x); v[1] = (short)f2bf(a.y);
  v[2] = (short)f2bf(a.z); v[3] = (short)f2bf(a.w);
  v[4] = (short)f2bf(b.x); v[5] = (short)f2bf(b.y);
  v[6] = (short)f2bf(b.z); v[7] = (short)f2bf(b.w);
  *(short8*)&d[(size_t)j * 8] = v;
}

__global__ __launch_bounds__(256) void k_cast5e(
    const float* s0, unsigned short* d0, int n0,
    const float* s1, unsigned short* d1, int n1,
    const float* s2, unsigned short* d2, int n2,
    const float* s3, unsigned short* d3, int n3,
    const float* s4, unsigned short* d4, int n4,
    int nbcast,
    const int* __restrict__ ids, const float* __restrict__ emb,
    const float* __restrict__ pe, float* __restrict__ rep,
    unsigned short* __restrict__ repb, float* __restrict__ partial,
    int* visits, int* active, float* entp) {
  if (blockIdx.x == 0) {
    if (threadIdx.x < NB * NE) visits[threadIdx.x] = 0;
    if (threadIdx.x < NB) active[threadIdx.x] = 1;
    if (threadIdx.x == 0) *entp = 0.f;
  }
  if ((int)blockIdx.x >= nbcast) {
    int j2 = blockIdx.x - nbcast;
    int rg = j2 & 15, b = j2 >> 4;
    int t = threadIdx.x;
    int c0 = t, c1 = t + 256;
    float p0 = 0.f, p1 = 0.f;
    for (int row = 0; row < 16; ++row) {
      int s = rg * 16 + row;
      int id = ids[b * NS + s];
      float sc = (id != 0) ? 22.627416997969522f : 0.f;  // sqrt(512), pad row zeroed
      float v0 = emb[(size_t)id * ND + c0] * sc + pe[(size_t)s * ND + c0];
      float v1 = emb[(size_t)id * ND + c1] * sc + pe[(size_t)s * ND + c1];
      size_t base = ((size_t)b * NS + s) * ND;
      rep[base + c0] = v0; rep[base + c1] = v1;
      repb[base + c0] = f2bf(v0); repb[base + c1] = f2bf(v1);
      p0 += v0; p1 += v1;
    }
    float* pp = partial + ((size_t)b * 16 + rg) * ND;
    pp[c0] = p0; pp[c1] = p1;
    return;
  }
  int j = blockIdx.x * 256 + threadIdx.x;
  if (j < n0) { cast8(s0, d0, j); return; }
  j -= n0;
  if (j < n1) { cast8(s1, d1, j); return; }
  j -= n1;
  if (j < n2) { cast8(s2, d2, j); return; }
  j -= n2;
  if (j < n3) { cast8(s3, d3, j); return; }
  j -= n3;
  if (j < n4) cast8(s4, d4, j);
}

// ---------------- router (1 block); summary computed from 16-row partials ----------------
__global__ __launch_bounds__(256) void k_router(const float* __restrict__ partial,
                                                const float* __restrict__ rw1,
                                                const float* __restrict__ rb1,
                                                const float* __restrict__ rw2,
                                                const float* __restrict__ rb2,
                                                int* visits, int* active,
                                                int* idx, int* go, float* ent_total) {
  __shared__ float sm[NB][ND];
  __shared__ float h[NB][NRH];
  __shared__ float lg[NB][NE + 1];
  int t = threadIdx.x;
  for (int i = t; i < NB * ND; i += 256) {
    int bb = i >> 9, d = i & 511;
    const float* pp = partial + ((size_t)bb * 16) * ND + d;
    float s = 0.f;
#pragma unroll
    for (int rg = 0; rg < 16; ++rg) s += pp[(size_t)rg * ND];
    sm[bb][d] = s * (1.f / NS);
  }
  __syncthreads();
  {
    const float* w = rw1 + (size_t)t * ND;
    float acc[NB];
#pragma unroll
    for (int b = 0; b < NB; ++b) acc[b] = rb1[t];
    for (int d = 0; d < ND; ++d) {
      float wv = w[d];
#pragma unroll
      for (int b = 0; b < NB; ++b) acc[b] += sm[b][d] * wv;
    }
#pragma unroll
    for (int b = 0; b < NB; ++b) h[b][t] = fmaxf(acc[b], 0.f);
  }
  __syncthreads();
  if (t < NB * (NE + 1)) {
    int b = t / (NE + 1), e = t % (NE + 1);
    const float* w = rw2 + e * NRH;
    float a = rb2[e];
    for (int r = 0; r < NRH; ++r) a += h[b][r] * w[r];
    lg[b][e] = a;
  }
  __syncthreads();
  if (t == 0) {
    int aprev[NB];
    int cnt = 0;
    for (int b = 0; b < NB; ++b) { aprev[b] = active[b]; cnt += aprev[b]; }
    float entsum = 0.f;
    for (int b = 0; b < NB; ++b) {
      float l[NE + 1];
      for (int e = 0; e < NE; ++e)
        l[e] = (visits[b * NE + e] >= MAXV) ? NEGV : lg[b][e];
      l[NE] = lg[b][NE];
      float m = l[0];
      for (int e = 1; e <= NE; ++e) m = fmaxf(m, l[e]);
      float z = 0.f, p[NE + 1];
      for (int e = 0; e <= NE; ++e) { p[e] = __expf(l[e] - m); z += p[e]; }
      float zi = 1.f / z, ent = 0.f;
      for (int e = 0; e <= NE; ++e) {
        float pp = p[e] * zi;
        ent -= pp * __logf(pp + 1e-9f);
      }
      if (aprev[b]) entsum += ent;
      int ch = 0; float bm = l[0];
      for (int e = 1; e <= NE; ++e) if (l[e] > bm) { bm = l[e]; ch = e; }
      int g = (aprev[b] && ch < NE) ? 1 : 0;
      int ix = g ? ch : 0;
      visits[b * NE + ix] += g;
      idx[b] = ix; go[b] = g; active[b] = g;
    }
    if (cnt > 0) *ent_total += entsum / (float)cnt;
  }
}

// ---------------- 64x64-tile bf16 MFMA expert GEMM, BK=64, depth-2 counted-vmcnt ----------------
// OUT: 0 = fp32 split-K partials (no bias), 1 = bf16 + bias (+relu), 2 = qkv-split.
// SK = split-K ways. grid (4*SK, N/64, NB). Fully gated.
// Staging swizzle (128B rows): LDS slot (row, chunk c) holds global chunk c^(row&7);
// read chunk (kk*4+g)^(row0&7) -> 8 bank-groups, 2-way conflict (free).
template <int OUT, int RELU, int SK>
__global__ __launch_bounds__(256) void k_gemm64p(
    const unsigned short* __restrict__ Aall, int sa,
    const unsigned short* __restrict__ Wall, const float* __restrict__ ball,
    float* __restrict__ Pall, unsigned short* __restrict__ Uall, int so,
    int N, int K,
    unsigned short* __restrict__ Qb, unsigned short* __restrict__ Kb,
    unsigned short* __restrict__ Vt,
    const int* __restrict__ go, const int* __restrict__ idx) {
  int b = blockIdx.z;
  if (!go[b]) return;
  int t = threadIdx.x;
  int lane = t & 63, w = t >> 6;
  int wm = (w >> 1) * 32, wn = (w & 1) * 32;
  int kc = blockIdx.x >> 2;
  int bm = (blockIdx.x & 3) * 64, bn = blockIdx.y * 64;
  int KC = K / SK;
  int lrow = (lane >> 4) * 4, lcol = lane & 15;
  const unsigned short* A = Aall + (size_t)b * sa + kc * KC;
  const unsigned short* W = Wall + (size_t)idx[b] * N * K + kc * KC;

  __shared__ __align__(16) unsigned short As[2][64][64];  // 16 KB
  __shared__ __align__(16) unsigned short Bs[2][64][64];  // 16 KB
  f32x4 acc[2][2];
#pragma unroll
  for (int i = 0; i < 2; ++i)
#pragma unroll
    for (int j = 0; j < 2; ++j) acc[i][j] = (f32x4){0.f, 0.f, 0.f, 0.f};

  // wave w stages rows [w*16, w*16+16); lane l -> row (l>>3), chunk (l&7)^((l>>3)&7)
  int ch8 = (lane & 7) ^ ((lane >> 3) & 7);
  const unsigned short* ga = A + (size_t)(bm + w * 16 + (lane >> 3)) * K + ch8 * 8;
  const unsigned short* gb = W + (size_t)(bn + w * 16 + (lane >> 3)) * K + ch8 * 8;

#define ISSUE64(slot, kt)                                            \
  gload16(ga + (size_t)(kt) * 64, &As[slot][w * 16][0]);             \
  gload16(ga + (size_t)(kt) * 64 + 8 * (size_t)K, &As[slot][w * 16 + 8][0]); \
  gload16(gb + (size_t)(kt) * 64, &Bs[slot][w * 16][0]);             \
  gload16(gb + (size_t)(kt) * 64 + 8 * (size_t)K, &Bs[slot][w * 16 + 8][0]);

  int nk = KC >> 6;  // >= 4 for all uses
  ISSUE64(0, 0)
  ISSUE64(1, 1)

  int row0 = lane & 15, g = lane >> 4;
  for (int it = 0; it < nk; ++it) {
    if (it < nk - 1) asm volatile("s_waitcnt vmcnt(4)" ::: "memory");
    else             asm volatile("s_waitcnt vmcnt(0)" ::: "memory");
    asm volatile("s_barrier" ::: "memory");  // all waves: tile it landed
    int sl = it & 1;
#pragma unroll
    for (int kk = 0; kk < 2; ++kk) {
      int co = ((kk * 4 + g) ^ (row0 & 7)) * 8;
      short8 a0 = *(const short8*)&As[sl][wm + row0][co];
      short8 a1 = *(const short8*)&As[sl][wm + 16 + row0][co];
      short8 b0 = *(const short8*)&Bs[sl][wn + row0][co];
      short8 b1 = *(const short8*)&Bs[sl][wn + 16 + row0][co];
      acc[0][0] = __builtin_amdgcn_mfma_f32_16x16x32_bf16(a0, b0, acc[0][0], 0, 0, 0);
      acc[0][1] = __builtin_amdgcn_mfma_f32_16x16x32_bf16(a0, b1, acc[0][1], 0, 0, 0);
      acc[1][0] = __builtin_amdgcn_mfma_f32_16x16x32_bf16(a1, b0, acc[1][0], 0, 0, 0);
      acc[1][1] = __builtin_amdgcn_mfma_f32_16x16x32_bf16(a1, b1, acc[1][1], 0, 0, 0);
    }
    asm volatile("s_barrier" ::: "memory");  // all waves done reading slot sl
    if (it + 2 < nk) { ISSUE64(sl, it + 2) }
  }
#undef ISSUE64

  if (OUT == 2) {
    const float* bias = ball + (size_t)idx[b] * N;
    int seg = bn >> 9;  // 0:Q 1:K 2:V — 64-tile never crosses a 512 boundary
#pragma unroll
    for (int nf = 0; nf < 2; ++nf) {
      int col = bn + wn + nf * 16 + lcol;
      float bv = bias[col];
      if (seg < 2) {
        unsigned short* dst = (seg == 0) ? Qb : Kb;
        int cc = col - seg * 512;
#pragma unroll
        for (int mf = 0; mf < 2; ++mf)
#pragma unroll
          for (int r = 0; r < 4; ++r) {
            int row = bm + wm + mf * 16 + lrow + r;
            dst[((size_t)b * NS + row) * ND + cc] = f2bf(acc[mf][nf][r] + bv);
          }
      } else {
        int dcol = col - 1024;
#pragma unroll
        for (int mf = 0; mf < 2; ++mf) {
          int s0 = bm + wm + mf * 16 + lrow;
          unsigned long long pk =
              (unsigned long long)f2bf(acc[mf][nf][0] + bv) |
              ((unsigned long long)f2bf(acc[mf][nf][1] + bv) << 16) |
              ((unsigned long long)f2bf(acc[mf][nf][2] + bv) << 32) |
              ((unsigned long long)f2bf(acc[mf][nf][3] + bv) << 48);
          *(unsigned long long*)&Vt[((size_t)b * 512 + dcol) * 256 + s0] = pk;
        }
      }
    }
  } else if (OUT == 1) {
    const float* bias = ball + (size_t)idx[b] * N;
#pragma unroll
    for (int nf = 0; nf < 2; ++nf) {
      int col = bn + wn + nf * 16 + lcol;
      float bv = bias[col];
#pragma unroll
      for (int mf = 0; mf < 2; ++mf) {
#pragma unroll
        for (int r = 0; r < 4; ++r) {
          int row = bm + wm + mf * 16 + lrow + r;
          float v = acc[mf][nf][r] + bv;
          if (RELU) v = fmaxf(v, 0.f);
          Uall[(size_t)b * so + (size_t)row * N + col] = f2bf(v);
        }
      }
    }
  } else {
    float* P = Pall + ((size_t)kc * NB + b) * ((size_t)NS * N);
#pragma unroll
    for (int nf = 0; nf < 2; ++nf) {
      int col = bn + wn + nf * 16 + lcol;
#pragma unroll
      for (int mf = 0; mf < 2; ++mf)
#pragma unroll
        for (int r = 0; r < 4; ++r)
          P[(size_t)(bm + wm + mf * 16 + lrow + r) * N + col] = acc[mf][nf][r];
    }
  }
}

// ---------------- MFMA flash attention: K/V direct from L2 (no staging), P-only LDS ----------------
__global__ __launch_bounds__(256) void k_attn2(const unsigned short* __restrict__ Qb,
                                               const unsigned short* __restrict__ Kb,
                                               const unsigned short* __restrict__ Vt,
                                               unsigned short* __restrict__ ctxb,
                                               const int* __restrict__ go) {
  int b = blockIdx.z, h = blockIdx.y, qt = blockIdx.x;
  if (!go[b]) return;  // ctx_b consumers are gated
  int t = threadIdx.x;
  __shared__ __align__(16) unsigned short ldsP[16384];  // P: 64 q-rows x 256 keys (32 KB)
  int lane = t & 63, w = t >> 6, g = lane >> 4, c = lane & 15;

  // Q fragments straight from global bf16
  short8 qf[2];
  {
    const unsigned short* qp = Qb + ((size_t)b * NS + qt * 64 + w * 16 + c) * ND + h * NDH;
    qf[0] = *(const short8*)&qp[g * 8];
    qf[1] = *(const short8*)&qp[32 + g * 8];
  }

  // S^T = K @ Q^T, K read directly from global (L2/L3-resident, freshly written)
  const unsigned short* kbase = Kb + ((size_t)b * NS) * ND + h * NDH;
  f32x4 sacc[16];
#pragma unroll
  for (int mf = 0; mf < 16; ++mf) sacc[mf] = (f32x4){0.f, 0.f, 0.f, 0.f};
#pragma unroll
  for (int mf = 0; mf < 16; ++mf) {
    int row = mf * 16 + c;
#pragma unroll
    for (int kd = 0; kd < 2; ++kd) {
      short8 kf = *(const short8*)&kbase[(size_t)row * ND + kd * 32 + g * 8];
      sacc[mf] = __builtin_amdgcn_mfma_f32_16x16x32_bf16(kf, qf[kd], sacc[mf], 0, 0, 0);
    }
  }

  float mx = -3.4e38f;
#pragma unroll
  for (int mf = 0; mf < 16; ++mf) {
#pragma unroll
    for (int r = 0; r < 4; ++r) {
      sacc[mf][r] *= 0.125f;
      mx = fmaxf(mx, sacc[mf][r]);
    }
  }
  mx = fmaxf(mx, __shfl_xor(mx, 16));
  mx = fmaxf(mx, __shfl_xor(mx, 32));
  float sum = 0.f;
#pragma unroll
  for (int mf = 0; mf < 16; ++mf)
#pragma unroll
    for (int r = 0; r < 4; ++r) {
      float p = __expf(sacc[mf][r] - mx);
      sacc[mf][r] = p;
      sum += p;
    }
  sum += __shfl_xor(sum, 16);
  sum += __shfl_xor(sum, 32);
  float zi = 1.f / sum;

  int q_l = w * 16 + c;
#pragma unroll
  for (int mf = 0; mf < 16; ++mf) {
    unsigned long long pk =
        (unsigned long long)f2bf(sacc[mf][0] * zi) |
        ((unsigned long long)f2bf(sacc[mf][1] * zi) << 16) |
        ((unsigned long long)f2bf(sacc[mf][2] * zi) << 32) |
        ((unsigned long long)f2bf(sacc[mf][3] * zi) << 48);
    *(unsigned long long*)&ldsP[q_l * 256 + ((mf * 16 + g * 4) ^ ((q_l & 7) << 3))] = pk;
  }
  __syncthreads();  // P visible (rows are wave-local; barrier kept for safety)

  // ctx = P @ V, V^T read directly from global
  f32x4 cacc[4];
#pragma unroll
  for (int nf = 0; nf < 4; ++nf) cacc[nf] = (f32x4){0.f, 0.f, 0.f, 0.f};
  const unsigned short* vbase = Vt + ((size_t)b * 512 + h * NDH) * 256;
#pragma unroll
  for (int ks = 0; ks < 8; ++ks) {
    int prow = w * 16 + c;
    short8 pf = *(const short8*)&ldsP[prow * 256 + ((ks * 32 + g * 8) ^ ((prow & 7) << 3))];
#pragma unroll
    for (int nf = 0; nf < 4; ++nf) {
      short8 vf = *(const short8*)&vbase[(size_t)(nf * 16 + c) * 256 + ks * 32 + g * 8];
      cacc[nf] = __builtin_amdgcn_mfma_f32_16x16x32_bf16(pf, vf, cacc[nf], 0, 0, 0);
    }
  }
#pragma unroll
  for (int nf = 0; nf < 4; ++nf)
#pragma unroll
    for (int r = 0; r < 4; ++r)
      ctxb[((size_t)b * NS + qt * 64 + w * 16 + g * 4 + r) * ND + h * NDH + nf * 16 + c] =
          f2bf(cacc[nf][r]);
}

// ---------------- partial-reduce + GEMM bias + residual + LayerNorm (+tag, +summary) ----------------
template <int NCH, int TAG, int SUMP>
__global__ __launch_bounds__(256) void k_ln_red(
    const float* __restrict__ res, const float* __restrict__ part,
    const float* __restrict__ gbias,
    const float* __restrict__ gall, const float* __restrict__ beall,
    const float* __restrict__ tagall,
    float* __restrict__ outf, unsigned short* __restrict__ outb,
    float* __restrict__ sump,
    const int* __restrict__ go, const int* __restrict__ idx) {
  int b = blockIdx.y;
  if (!go[b]) return;
  int rg = blockIdx.x;
  int w = threadIdx.x >> 6, l = threadIdx.x & 63;
  int ix = idx[b];
  int d = l * 8;
  float gb8[8], gg[8], bb[8];
  {
    float4 a0 = *(const float4*)&gbias[ix * ND + d];
    float4 a1 = *(const float4*)&gbias[ix * ND + d + 4];
    gb8[0] = a0.x; gb8[1] = a0.y; gb8[2] = a0.z; gb8[3] = a0.w;
    gb8[4] = a1.x; gb8[5] = a1.y; gb8[6] = a1.z; gb8[7] = a1.w;
    float4 g0 = *(const float4*)&gall[ix * ND + d];
    float4 g1 = *(const float4*)&gall[ix * ND + d + 4];
    gg[0] = g0.x; gg[1] = g0.y; gg[2] = g0.z; gg[3] = g0.w;
    gg[4] = g1.x; gg[5] = g1.y; gg[6] = g1.z; gg[7] = g1.w;
    float4 b0 = *(const float4*)&beall[ix * ND + d];
    float4 b1 = *(const float4*)&beall[ix * ND + d + 4];
    bb[0] = b0.x; bb[1] = b0.y; bb[2] = b0.z; bb[3] = b0.w;
    bb[4] = b1.x; bb[5] = b1.y; bb[6] = b1.z; bb[7] = b1.w;
    if (TAG) {
      float4 t0 = *(const float4*)&tagall[ix * ND + d];
      float4 t1 = *(const float4*)&tagall[ix * ND + d + 4];
      bb[0] += t0.x; bb[1] += t0.y; bb[2] += t0.z; bb[3] += t0.w;
      bb[4] += t1.x; bb[5] += t1.y; bb[6] += t1.z; bb[7] += t1.w;
    }
  }
  float ps[8] = {0.f, 0.f, 0.f, 0.f, 0.f, 0.f, 0.f, 0.f};
  const size_t CSTRIDE = (size_t)NB * NS * ND;
  for (int rr = 0; rr < 4; ++rr) {
    int s = rg * 16 + w * 4 + rr;
    size_t base = ((size_t)b * NS + s) * ND;
    float4 x0 = *(const float4*)&res[base + d];
    float4 x1 = *(const float4*)&res[base + d + 4];
    float v[8] = {x0.x + gb8[0], x0.y + gb8[1], x0.z + gb8[2], x0.w + gb8[3],
                  x1.x + gb8[4], x1.y + gb8[5], x1.z + gb8[6], x1.w + gb8[7]};
#pragma unroll
    for (int c = 0; c < NCH; ++c) {
      const float* pc = part + c * CSTRIDE + base;
      float4 p0 = *(const float4*)&pc[d];
      float4 p1 = *(const float4*)&pc[d + 4];
      v[0] += p0.x; v[1] += p0.y; v[2] += p0.z; v[3] += p0.w;
      v[4] += p1.x; v[5] += p1.y; v[6] += p1.z; v[7] += p1.w;
    }
    float sum = 0.f;
#pragma unroll
    for (int j = 0; j < 8; ++j) sum += v[j];
#pragma unroll
    for (int off = 1; off < 64; off <<= 1) sum += __shfl_xor(sum, off);
    float mu = sum * (1.f / ND);
    float var = 0.f;
#pragma unroll
    for (int j = 0; j < 8; ++j) { v[j] -= mu; var += v[j] * v[j]; }
#pragma unroll
    for (int off = 1; off < 64; off <<= 1) var += __shfl_xor(var, off);
    float rs = rsqrtf(var * (1.f / ND) + 1e-5f);
    float o[8];
    short8 ob;
#pragma unroll
    for (int j = 0; j < 8; ++j) {
      o[j] = v[j] * rs * gg[j] + bb[j];
      if (SUMP) ps[j] += o[j];
      ob[j] = (short)f2bf(o[j]);
    }
    *(float4*)&outf[base + d] = (float4){o[0], o[1], o[2], o[3]};
    *(float4*)&outf[base + d + 4] = (float4){o[4], o[5], o[6], o[7]};
    *(short8*)&outb[base + d] = ob;
  }
  if (SUMP) {
    __shared__ float pl[4][ND];
#pragma unroll
    for (int j = 0; j < 8; ++j) pl[w][d + j] = ps[j];
    __syncthreads();
    if (w == 0) {
      float* pp = sump + ((size_t)b * 16 + rg) * ND;
#pragma unroll
      for (int j = 0; j < 8; ++j)
        pp[d + j] = pl[0][d + j] + pl[1][d + j] + pl[2][d + j] + pl[3][d + j];
    }
  }
}

// ---------------- LM head: 256x256-tile bf16 MFMA GEMM, 8 waves, counted-vmcnt depth-2 ----------------
__global__ __launch_bounds__(512, 2) void k_lmhead256(const unsigned short* __restrict__ Ab,
                                                      const unsigned short* __restrict__ Wb,
                                                      const float* __restrict__ bias,
                                                      float* __restrict__ out,
                                                      const float* __restrict__ entp) {
  if (blockIdx.x == 0 && threadIdx.x == 0)
    out[(size_t)NB * NS * NV] = *entp;  // fused k_ent
  int id = blockIdx.x;
  int swz = (id & 7) * 125 + (id >> 3);  // bijective: 1000 = 8 * 125
  int bm = (swz % 8) * 256;
  int bn = (swz / 8) * 256;

  __shared__ __align__(16) unsigned short As[2][256][32];
  __shared__ __align__(16) unsigned short Bs[2][256][32];
  int t = threadIdx.x;
  int lane = t & 63, w = t >> 6;
  int wm = (w >> 2) * 128, wn = (w & 3) * 64;
  f32x4 acc[8][4];
#pragma unroll
  for (int i = 0; i < 8; ++i)
#pragma unroll
    for (int j = 0; j < 4; ++j) acc[i][j] = (f32x4){0.f, 0.f, 0.f, 0.f};

  const unsigned short* ga = Ab + (size_t)(bm + w * 32 + (lane >> 2)) * ND + swzc(lane) * 8;
  const unsigned short* gb = Wb + (size_t)(bn + w * 32 + (lane >> 2)) * ND + swzc(lane) * 8;

#define ISSUEL(slot, kt)                                           \
  gload16(ga + (kt) * 32, &As[slot][w * 32][0]);                   \
  gload16(ga + (kt) * 32 + 16 * ND, &As[slot][w * 32 + 16][0]);    \
  gload16(gb + (kt) * 32, &Bs[slot][w * 32][0]);                   \
  gload16(gb + (kt) * 32 + 16 * ND, &Bs[slot][w * 32 + 16][0]);

  ISSUEL(0, 0)
  ISSUEL(1, 1)

  int row0 = lane & 15;
  int cs = ((lane >> 4) ^ ((row0 >> 1) & 3)) * 8;
  for (int it = 0; it < 16; ++it) {
    if (it < 15) asm volatile("s_waitcnt vmcnt(4)" ::: "memory");
    else         asm volatile("s_waitcnt vmcnt(0)" ::: "memory");
    asm volatile("s_barrier" ::: "memory");  // tile it landed for all waves
    int sl = it & 1;
    short8 a[8], bfr[4];
#pragma unroll
    for (int mf = 0; mf < 8; ++mf)
      a[mf] = *(const short8*)&As[sl][wm + mf * 16 + row0][cs];
#pragma unroll
    for (int nf = 0; nf < 4; ++nf)
      bfr[nf] = *(const short8*)&Bs[sl][wn + nf * 16 + row0][cs];
#pragma unroll
    for (int mf = 0; mf < 8; ++mf)
#pragma unroll
      for (int nf = 0; nf < 4; ++nf)
        acc[mf][nf] = __builtin_amdgcn_mfma_f32_16x16x32_bf16(a[mf], bfr[nf], acc[mf][nf], 0, 0, 0);
    asm volatile("s_barrier" ::: "memory");  // reads of slot sl done
    if (it + 2 < 16) { ISSUEL(sl, it + 2) }
  }
#undef ISSUEL

  int lrow = (lane >> 4) * 4, lcol = lane & 15;
#pragma unroll
  for (int nf = 0; nf < 4; ++nf) {
    int col = bn + wn + nf * 16 + lcol;
    float bv = bias[col];
#pragma unroll
    for (int mf = 0; mf < 8; ++mf) {
#pragma unroll
      for (int r = 0; r < 4; ++r) {
        int row = bm + wm + mf * 16 + lrow + r;
        out[(size_t)row * NV + col] = acc[mf][nf][r] + bv;
      }
    }
  }
}

extern "C" void kernel_launch(void* const* d_in, const int* in_sizes, int n_in,
                              void* d_out, int out_size, void* d_ws, size_t ws_size,
                              hipStream_t stream) {
  const int* ids   = (const int*)d_in[0];
  const float* emb = (const float*)d_in[1];
  const float* pe  = (const float*)d_in[2];
  const float* Wqkv = (const float*)d_in[3];
  const float* bqkv = (const float*)d_in[4];
  const float* Wo   = (const float*)d_in[5];
  const float* bo   = (const float*)d_in[6];
  const float* W1   = (const float*)d_in[7];
  const float* b1   = (const float*)d_in[8];
  const float* W2   = (const float*)d_in[9];
  const float* b2   = (const float*)d_in[10];
  const float* g1   = (const float*)d_in[11];
  const float* be1  = (const float*)d_in[12];
  const float* g2   = (const float*)d_in[13];
  const float* be2  = (const float*)d_in[14];
  const float* tag  = (const float*)d_in[15];
  const float* rw1  = (const float*)d_in[16];
  const float* rb1  = (const float*)d_in[17];
  const float* rw2  = (const float*)d_in[18];
  const float* rb2  = (const float*)d_in[19];
  const float* lmw  = (const float*)d_in[20];
  const float* lmb  = (const float*)d_in[21];
  float* out = (float*)d_out;

  float* ws = (float*)d_ws;
  size_t o = 0;
  float* rep = ws + o;  o += (size_t)NB * NS * ND;           // fp32
  float* x1  = ws + o;  o += (size_t)NB * NS * ND;
  float* partk = ws + o; o += (size_t)4 * NB * NS * ND;       // split-K partials
  float* partial = ws + o; o += (size_t)NB * 16 * ND;         // summary partials
  int* visits = (int*)(ws + o); o += 1024;
  int* active = visits + NB * NE;
  int* idx = active + NB;
  int* go = idx + NB;
  float* entp = (float*)(go + NB);

  unsigned short* us = (unsigned short*)(ws + o);
  size_t uo = 0;
  unsigned short* rep_b = us + uo; uo += (size_t)NB * NS * ND;
  unsigned short* x1_b  = us + uo; uo += (size_t)NB * NS * ND;
  unsigned short* ctx_b = us + uo; uo += (size_t)NB * NS * ND;
  unsigned short* Qb    = us + uo; uo += (size_t)NB * NS * ND;
  unsigned short* Kb    = us + uo; uo += (size_t)NB * NS * ND;
  unsigned short* Vt    = us + uo; uo += (size_t)NB * NS * ND;
  unsigned short* hid_b = us + uo; uo += (size_t)NB * NS * NFF;
  unsigned short* Wqkv_b = us + uo; uo += (size_t)NE * 3 * ND * ND;
  unsigned short* Wo_b   = us + uo; uo += (size_t)NE * ND * ND;
  unsigned short* W1_b   = us + uo; uo += (size_t)NE * NFF * ND;
  unsigned short* W2_b   = us + uo; uo += (size_t)NE * ND * NFF;
  unsigned short* lmw_b  = us + uo; uo += (size_t)NV * ND;

  // fused weight pre-casts + state init + embedding (deterministic every call)
  {
    int n0 = NE * 3 * ND * ND / 8, n1 = NE * ND * ND / 8, n2 = NE * NFF * ND / 8,
        n3 = NE * ND * NFF / 8, n4 = NV * ND / 8;
    int nbcast = (n0 + n1 + n2 + n3 + n4) / 256;
    k_cast5e<<<nbcast + 16 * NB, 256, 0, stream>>>(
        Wqkv, Wqkv_b, n0, Wo, Wo_b, n1, W1, W1_b, n2, W2, W2_b, n3, lmw, lmw_b, n4,
        nbcast, ids, emb, pe, rep, rep_b, partial, visits, active, entp);
  }

  for (int step = 0; step < 4; ++step) {
    k_router<<<1, 256, 0, stream>>>(partial, rw1, rb1, rw2, rb2,
                                    visits, active, idx, go, entp);
    // qkv: rep_b @ Wqkv^T + bqkv -> Qb/Kb bf16, Vt transposed (768 blocks)
    k_gemm64p<2, 0, 1><<<dim3(4, 24, NB), 256, 0, stream>>>(
        rep_b, NS * ND, Wqkv_b, bqkv, nullptr, nullptr, 0, 3 * ND, ND,
        Qb, Kb, Vt, go, idx);
    // attention (de-staged, P-only LDS)
    k_attn2<<<dim3(4, NH, NB), 256, 0, stream>>>(Qb, Kb, Vt, ctx_b, go);
    // wo: ctx @ Wo^T -> 2-way split-K partials (512 blocks)
    k_gemm64p<0, 0, 2><<<dim3(8, 8, NB), 256, 0, stream>>>(
        ctx_b, NS * ND, Wo_b, nullptr, partk, nullptr, 0, ND, ND,
        nullptr, nullptr, nullptr, go, idx);
    // x1 = LN(rep + sum(partials) + bo)
    k_ln_red<2, 0, 0><<<dim3(16, NB), 256, 0, stream>>>(
        rep, partk, bo, g1, be1, nullptr, x1, x1_b, nullptr, go, idx);
    // hid = relu(x1 @ W1^T + b1) -> bf16 (1024 blocks)
    k_gemm64p<1, 1, 1><<<dim3(4, 32, NB), 256, 0, stream>>>(
        x1_b, NS * ND, W1_b, b1, nullptr, hid_b, NS * NFF, NFF, ND,
        nullptr, nullptr, nullptr, go, idx);
    // w2: hid @ W2^T -> 4-way split-K partials (1024 blocks)
    k_gemm64p<0, 0, 4><<<dim3(16, 8, NB), 256, 0, stream>>>(
        hid_b, NS * NFF, W2_b, nullptr, partk, nullptr, 0, ND, NFF,
        nullptr, nullptr, nullptr, go, idx);
    // rep = LN(x1 + sum(partials) + b2) + tag, + 16-row summary partials
    k_ln_red<4, 1, 1><<<dim3(16, NB), 256, 0, stream>>>(
        x1, partk, b2, g2, be2, tag, rep, rep_b, partial, go, idx);
  }

  k_lmhead256<<<1000, 512, 0, stream>>>(rep_b, lmw_b, lmb, out, entp);
}

// Round 13
// 590.248 us; speedup vs baseline: 1.0087x; 1.0087x over previous
//
#include <hip/hip_runtime.h>
#include <hip/hip_bf16.h>

#define NB 8
#define NS 256
#define ND 512
#define NH 8
#define NDH 64
#define NFF 2048
#define NE 8
#define NV 32000
#define NRH 256
#define MAXV 2
#define NEGV (-1e9f)

typedef __attribute__((ext_vector_type(8))) short short8;
typedef __attribute__((ext_vector_type(4))) float f32x4;

__device__ __forceinline__ unsigned short f2bf(float x) {
  unsigned int u = __float_as_uint(x);
  u = (u + 0x7fffu + ((u >> 16) & 1u)) >> 16;
  return (unsigned short)u;
}

// async global->LDS, 16 bytes per lane; LDS dest is wave-uniform base + lane*16
__device__ __forceinline__ void gload16(const unsigned short* g, unsigned short* l) {
  __builtin_amdgcn_global_load_lds(
      (const __attribute__((address_space(1))) unsigned int*)g,
      (__attribute__((address_space(3))) unsigned int*)l, 16, 0, 0);
}

// 32-col-row staging swizzle (lmhead): lane -> chunk (l&3) ^ ((l>>3)&3)
__device__ __forceinline__ int swzc(int lane) {
  return (lane & 3) ^ ((lane >> 3) & 3);
}

// ---------------- fused: weight casts + state init + embedding ----------------
__device__ __forceinline__ void cast8(const float* s, unsigned short* d, int j) {
  const float4* s4 = (const float4*)s;
  float4 a = s4[j * 2], b = s4[j * 2 + 1];
  short8 v;
  v[0] = (short)f2bf(a.x); v[1] = (short)f2bf(a.y);
  v[2] = (short)f2bf(a.z); v[3] = (short)f2bf(a.w);
  v[4] = (short)f2bf(b.x); v[5] = (short)f2bf(b.y);
  v[6] = (short)f2bf(b.z); v[7] = (short)f2bf(b.w);
  *(short8*)&d[(size_t)j * 8] = v;
}

__global__ __launch_bounds__(256) void k_cast5e(
    const float* s0, unsigned short* d0, int n0,
    const float* s1, unsigned short* d1, int n1,
    const float* s2, unsigned short* d2, int n2,
    const float* s3, unsigned short* d3, int n3,
    const float* s4, unsigned short* d4, int n4,
    int nbcast,
    const int* __restrict__ ids, const float* __restrict__ emb,
    const float* __restrict__ pe, float* __restrict__ rep,
    unsigned short* __restrict__ repb, float* __restrict__ partial,
    int* visits, int* active, float* entp) {
  if (blockIdx.x == 0) {
    if (threadIdx.x < NB * NE) visits[threadIdx.x] = 0;
    if (threadIdx.x < NB) active[threadIdx.x] = 1;
    if (threadIdx.x == 0) *entp = 0.f;
  }
  if ((int)blockIdx.x >= nbcast) {
    int j2 = blockIdx.x - nbcast;
    int rg = j2 & 15, b = j2 >> 4;
    int t = threadIdx.x;
    int c0 = t, c1 = t + 256;
    float p0 = 0.f, p1 = 0.f;
    for (int row = 0; row < 16; ++row) {
      int s = rg * 16 + row;
      int id = ids[b * NS + s];
      float sc = (id != 0) ? 22.627416997969522f : 0.f;  // sqrt(512), pad row zeroed
      float v0 = emb[(size_t)id * ND + c0] * sc + pe[(size_t)s * ND + c0];
      float v1 = emb[(size_t)id * ND + c1] * sc + pe[(size_t)s * ND + c1];
      size_t base = ((size_t)b * NS + s) * ND;
      rep[base + c0] = v0; rep[base + c1] = v1;
      repb[base + c0] = f2bf(v0); repb[base + c1] = f2bf(v1);
      p0 += v0; p1 += v1;
    }
    float* pp = partial + ((size_t)b * 16 + rg) * ND;
    pp[c0] = p0; pp[c1] = p1;
    return;
  }
  int j = blockIdx.x * 256 + threadIdx.x;
  if (j < n0) { cast8(s0, d0, j); return; }
  j -= n0;
  if (j < n1) { cast8(s1, d1, j); return; }
  j -= n1;
  if (j < n2) { cast8(s2, d2, j); return; }
  j -= n2;
  if (j < n3) { cast8(s3, d3, j); return; }
  j -= n3;
  if (j < n4) cast8(s4, d4, j);
}

// ---------------- router (1 block); summary computed from 16-row partials ----------------
__global__ __launch_bounds__(256) void k_router(const float* __restrict__ partial,
                                                const float* __restrict__ rw1,
                                                const float* __restrict__ rb1,
                                                const float* __restrict__ rw2,
                                                const float* __restrict__ rb2,
                                                int* visits, int* active,
                                                int* idx, int* go, float* ent_total) {
  __shared__ float sm[NB][ND];
  __shared__ float h[NB][NRH];
  __shared__ float lg[NB][NE + 1];
  int t = threadIdx.x;
  for (int i = t; i < NB * ND; i += 256) {
    int bb = i >> 9, d = i & 511;
    const float* pp = partial + ((size_t)bb * 16) * ND + d;
    float s = 0.f;
#pragma unroll
    for (int rg = 0; rg < 16; ++rg) s += pp[(size_t)rg * ND];
    sm[bb][d] = s * (1.f / NS);
  }
  __syncthreads();
  {
    const float* w = rw1 + (size_t)t * ND;
    float acc[NB];
#pragma unroll
    for (int b = 0; b < NB; ++b) acc[b] = rb1[t];
    for (int d = 0; d < ND; ++d) {
      float wv = w[d];
#pragma unroll
      for (int b = 0; b < NB; ++b) acc[b] += sm[b][d] * wv;
    }
#pragma unroll
    for (int b = 0; b < NB; ++b) h[b][t] = fmaxf(acc[b], 0.f);
  }
  __syncthreads();
  if (t < NB * (NE + 1)) {
    int b = t / (NE + 1), e = t % (NE + 1);
    const float* w = rw2 + e * NRH;
    float a = rb2[e];
    for (int r = 0; r < NRH; ++r) a += h[b][r] * w[r];
    lg[b][e] = a;
  }
  __syncthreads();
  if (t == 0) {
    int aprev[NB];
    int cnt = 0;
    for (int b = 0; b < NB; ++b) { aprev[b] = active[b]; cnt += aprev[b]; }
    float entsum = 0.f;
    for (int b = 0; b < NB; ++b) {
      float l[NE + 1];
      for (int e = 0; e < NE; ++e)
        l[e] = (visits[b * NE + e] >= MAXV) ? NEGV : lg[b][e];
      l[NE] = lg[b][NE];
      float m = l[0];
      for (int e = 1; e <= NE; ++e) m = fmaxf(m, l[e]);
      float z = 0.f, p[NE + 1];
      for (int e = 0; e <= NE; ++e) { p[e] = __expf(l[e] - m); z += p[e]; }
      float zi = 1.f / z, ent = 0.f;
      for (int e = 0; e <= NE; ++e) {
        float pp = p[e] * zi;
        ent -= pp * __logf(pp + 1e-9f);
      }
      if (aprev[b]) entsum += ent;
      int ch = 0; float bm = l[0];
      for (int e = 1; e <= NE; ++e) if (l[e] > bm) { bm = l[e]; ch = e; }
      int g = (aprev[b] && ch < NE) ? 1 : 0;
      int ix = g ? ch : 0;
      visits[b * NE + ix] += g;
      idx[b] = ix; go[b] = g; active[b] = g;
    }
    if (cnt > 0) *ent_total += entsum / (float)cnt;
  }
}

// ---------------- 64x64-tile bf16 MFMA expert GEMM, BK=64, depth-2 counted-vmcnt ----------------
// OUT: 0 = fp32 split-K partials (no bias), 1 = bf16 + bias (+relu), 2 = qkv-split.
// SK = split-K ways. grid (4*SK, N/64, NB). Fully gated.
template <int OUT, int RELU, int SK>
__global__ __launch_bounds__(256) void k_gemm64p(
    const unsigned short* __restrict__ Aall, int sa,
    const unsigned short* __restrict__ Wall, const float* __restrict__ ball,
    float* __restrict__ Pall, unsigned short* __restrict__ Uall, int so,
    int N, int K,
    unsigned short* __restrict__ Qb, unsigned short* __restrict__ Kb,
    unsigned short* __restrict__ Vt,
    const int* __restrict__ go, const int* __restrict__ idx) {
  int b = blockIdx.z;
  if (!go[b]) return;
  int t = threadIdx.x;
  int lane = t & 63, w = t >> 6;
  int wm = (w >> 1) * 32, wn = (w & 1) * 32;
  int kc = blockIdx.x >> 2;
  int bm = (blockIdx.x & 3) * 64, bn = blockIdx.y * 64;
  int KC = K / SK;
  int lrow = (lane >> 4) * 4, lcol = lane & 15;
  const unsigned short* A = Aall + (size_t)b * sa + kc * KC;
  const unsigned short* W = Wall + (size_t)idx[b] * N * K + kc * KC;

  __shared__ __align__(16) unsigned short As[2][64][64];  // 16 KB
  __shared__ __align__(16) unsigned short Bs[2][64][64];  // 16 KB
  f32x4 acc[2][2];
#pragma unroll
  for (int i = 0; i < 2; ++i)
#pragma unroll
    for (int j = 0; j < 2; ++j) acc[i][j] = (f32x4){0.f, 0.f, 0.f, 0.f};

  // wave w stages rows [w*16, w*16+16); lane l -> row (l>>3), chunk (l&7)^((l>>3)&7)
  int ch8 = (lane & 7) ^ ((lane >> 3) & 7);
  const unsigned short* ga = A + (size_t)(bm + w * 16 + (lane >> 3)) * K + ch8 * 8;
  const unsigned short* gb = W + (size_t)(bn + w * 16 + (lane >> 3)) * K + ch8 * 8;

#define ISSUE64(slot, kt)                                            \
  gload16(ga + (size_t)(kt) * 64, &As[slot][w * 16][0]);             \
  gload16(ga + (size_t)(kt) * 64 + 8 * (size_t)K, &As[slot][w * 16 + 8][0]); \
  gload16(gb + (size_t)(kt) * 64, &Bs[slot][w * 16][0]);             \
  gload16(gb + (size_t)(kt) * 64 + 8 * (size_t)K, &Bs[slot][w * 16 + 8][0]);

  int nk = KC >> 6;  // >= 4 for all uses
  ISSUE64(0, 0)
  ISSUE64(1, 1)

  int row0 = lane & 15, g = lane >> 4;
  for (int it = 0; it < nk; ++it) {
    if (it < nk - 1) asm volatile("s_waitcnt vmcnt(4)" ::: "memory");
    else             asm volatile("s_waitcnt vmcnt(0)" ::: "memory");
    asm volatile("s_barrier" ::: "memory");  // all waves: tile it landed
    int sl = it & 1;
    __builtin_amdgcn_s_setprio(1);
#pragma unroll
    for (int kk = 0; kk < 2; ++kk) {
      int co = ((kk * 4 + g) ^ (row0 & 7)) * 8;
      short8 a0 = *(const short8*)&As[sl][wm + row0][co];
      short8 a1 = *(const short8*)&As[sl][wm + 16 + row0][co];
      short8 b0 = *(const short8*)&Bs[sl][wn + row0][co];
      short8 b1 = *(const short8*)&Bs[sl][wn + 16 + row0][co];
      acc[0][0] = __builtin_amdgcn_mfma_f32_16x16x32_bf16(a0, b0, acc[0][0], 0, 0, 0);
      acc[0][1] = __builtin_amdgcn_mfma_f32_16x16x32_bf16(a0, b1, acc[0][1], 0, 0, 0);
      acc[1][0] = __builtin_amdgcn_mfma_f32_16x16x32_bf16(a1, b0, acc[1][0], 0, 0, 0);
      acc[1][1] = __builtin_amdgcn_mfma_f32_16x16x32_bf16(a1, b1, acc[1][1], 0, 0, 0);
    }
    __builtin_amdgcn_s_setprio(0);
    asm volatile("s_barrier" ::: "memory");  // all waves done reading slot sl
    if (it + 2 < nk) { ISSUE64(sl, it + 2) }
  }
#undef ISSUE64

  if (OUT == 2) {
    const float* bias = ball + (size_t)idx[b] * N;
    int seg = bn >> 9;  // 0:Q 1:K 2:V — 64-tile never crosses a 512 boundary
#pragma unroll
    for (int nf = 0; nf < 2; ++nf) {
      int col = bn + wn + nf * 16 + lcol;
      float bv = bias[col];
      if (seg < 2) {
        unsigned short* dst = (seg == 0) ? Qb : Kb;
        int cc = col - seg * 512;
#pragma unroll
        for (int mf = 0; mf < 2; ++mf)
#pragma unroll
          for (int r = 0; r < 4; ++r) {
            int row = bm + wm + mf * 16 + lrow + r;
            dst[((size_t)b * NS + row) * ND + cc] = f2bf(acc[mf][nf][r] + bv);
          }
      } else {
        int dcol = col - 1024;
#pragma unroll
        for (int mf = 0; mf < 2; ++mf) {
          int s0 = bm + wm + mf * 16 + lrow;
          unsigned long long pk =
              (unsigned long long)f2bf(acc[mf][nf][0] + bv) |
              ((unsigned long long)f2bf(acc[mf][nf][1] + bv) << 16) |
              ((unsigned long long)f2bf(acc[mf][nf][2] + bv) << 32) |
              ((unsigned long long)f2bf(acc[mf][nf][3] + bv) << 48);
          *(unsigned long long*)&Vt[((size_t)b * 512 + dcol) * 256 + s0] = pk;
        }
      }
    }
  } else if (OUT == 1) {
    const float* bias = ball + (size_t)idx[b] * N;
#pragma unroll
    for (int nf = 0; nf < 2; ++nf) {
      int col = bn + wn + nf * 16 + lcol;
      float bv = bias[col];
#pragma unroll
      for (int mf = 0; mf < 2; ++mf) {
#pragma unroll
        for (int r = 0; r < 4; ++r) {
          int row = bm + wm + mf * 16 + lrow + r;
          float v = acc[mf][nf][r] + bv;
          if (RELU) v = fmaxf(v, 0.f);
          Uall[(size_t)b * so + (size_t)row * N + col] = f2bf(v);
        }
      }
    }
  } else {
    float* P = Pall + ((size_t)kc * NB + b) * ((size_t)NS * N);
#pragma unroll
    for (int nf = 0; nf < 2; ++nf) {
      int col = bn + wn + nf * 16 + lcol;
#pragma unroll
      for (int mf = 0; mf < 2; ++mf)
#pragma unroll
        for (int r = 0; r < 4; ++r)
          P[(size_t)(bm + wm + mf * 16 + lrow + r) * N + col] = acc[mf][nf][r];
    }
  }
}

// ---------------- MFMA flash attention, staged K/V (round-11 version) ----------------
__global__ __launch_bounds__(256) void k_attn2(const unsigned short* __restrict__ Qb,
                                               const unsigned short* __restrict__ Kb,
                                               const unsigned short* __restrict__ Vt,
                                               unsigned short* __restrict__ ctxb,
                                               const int* __restrict__ go) {
  int b = blockIdx.z, h = blockIdx.y, qt = blockIdx.x;
  if (!go[b]) return;  // ctx_b consumers are gated
  int t = threadIdx.x;
  __shared__ __align__(16) unsigned short lds0[16384];  // K then P
  __shared__ __align__(16) unsigned short lds1[16384];  // V^T
  int lane = t & 63, w = t >> 6, g = lane >> 4, c = lane & 15;

#pragma unroll
  for (int i = 0; i < 8; ++i) {
    int task = i * 256 + t;
    int k = task >> 3, cc = task & 7;
    short8 v = *(const short8*)&Kb[((size_t)b * NS + k) * ND + h * NDH + cc * 8];
    *(short8*)&lds0[k * 64 + ((cc * 8) ^ ((k & 7) << 3))] = v;
  }
#pragma unroll
  for (int i = 0; i < 8; ++i) {
    int task = i * 256 + t;
    int d = task >> 5, kc = task & 31;
    short8 v = *(const short8*)&Vt[((size_t)b * 512 + h * NDH + d) * 256 + kc * 8];
    *(short8*)&lds1[d * 256 + ((kc * 8) ^ ((d & 7) << 3))] = v;
  }
  short8 qf[2];
  {
    const unsigned short* qp = Qb + ((size_t)b * NS + qt * 64 + w * 16 + c) * ND + h * NDH;
    qf[0] = *(const short8*)&qp[g * 8];
    qf[1] = *(const short8*)&qp[32 + g * 8];
  }
  __syncthreads();

  f32x4 sacc[16];
#pragma unroll
  for (int mf = 0; mf < 16; ++mf) sacc[mf] = (f32x4){0.f, 0.f, 0.f, 0.f};
#pragma unroll
  for (int mf = 0; mf < 16; ++mf) {
#pragma unroll
    for (int kd = 0; kd < 2; ++kd) {
      int row = mf * 16 + c;
      short8 kf = *(const short8*)&lds0[row * 64 + ((kd * 32 + g * 8) ^ ((row & 7) << 3))];
      sacc[mf] = __builtin_amdgcn_mfma_f32_16x16x32_bf16(kf, qf[kd], sacc[mf], 0, 0, 0);
    }
  }
  __syncthreads();  // lds0 becomes P

  float mx = -3.4e38f;
#pragma unroll
  for (int mf = 0; mf < 16; ++mf) {
#pragma unroll
    for (int r = 0; r < 4; ++r) {
      sacc[mf][r] *= 0.125f;
      mx = fmaxf(mx, sacc[mf][r]);
    }
  }
  mx = fmaxf(mx, __shfl_xor(mx, 16));
  mx = fmaxf(mx, __shfl_xor(mx, 32));
  float sum = 0.f;
#pragma unroll
  for (int mf = 0; mf < 16; ++mf)
#pragma unroll
    for (int r = 0; r < 4; ++r) {
      float p = __expf(sacc[mf][r] - mx);
      sacc[mf][r] = p;
      sum += p;
    }
  sum += __shfl_xor(sum, 16);
  sum += __shfl_xor(sum, 32);
  float zi = 1.f / sum;

  int q_l = w * 16 + c;
#pragma unroll
  for (int mf = 0; mf < 16; ++mf) {
    unsigned long long pk =
        (unsigned long long)f2bf(sacc[mf][0] * zi) |
        ((unsigned long long)f2bf(sacc[mf][1] * zi) << 16) |
        ((unsigned long long)f2bf(sacc[mf][2] * zi) << 32) |
        ((unsigned long long)f2bf(sacc[mf][3] * zi) << 48);
    *(unsigned long long*)&lds0[q_l * 256 + ((mf * 16 + g * 4) ^ ((q_l & 7) << 3))] = pk;
  }

  f32x4 cacc[4];
#pragma unroll
  for (int nf = 0; nf < 4; ++nf) cacc[nf] = (f32x4){0.f, 0.f, 0.f, 0.f};
#pragma unroll
  for (int ks = 0; ks < 8; ++ks) {
    int prow = w * 16 + c;
    short8 pf = *(const short8*)&lds0[prow * 256 + ((ks * 32 + g * 8) ^ ((prow & 7) << 3))];
#pragma unroll
    for (int nf = 0; nf < 4; ++nf) {
      int vrow = nf * 16 + c;
      short8 vf = *(const short8*)&lds1[vrow * 256 + ((ks * 32 + g * 8) ^ ((vrow & 7) << 3))];
      cacc[nf] = __builtin_amdgcn_mfma_f32_16x16x32_bf16(pf, vf, cacc[nf], 0, 0, 0);
    }
  }
#pragma unroll
  for (int nf = 0; nf < 4; ++nf)
#pragma unroll
    for (int r = 0; r < 4; ++r)
      ctxb[((size_t)b * NS + qt * 64 + w * 16 + g * 4 + r) * ND + h * NDH + nf * 16 + c] =
          f2bf(cacc[nf][r]);
}

// ---------------- partial-reduce + GEMM bias + residual + LayerNorm (+tag, +summary) ----------------
template <int NCH, int TAG, int SUMP>
__global__ __launch_bounds__(256) void k_ln_red(
    const float* __restrict__ res, const float* __restrict__ part,
    const float* __restrict__ gbias,
    const float* __restrict__ gall, const float* __restrict__ beall,
    const float* __restrict__ tagall,
    float* __restrict__ outf, unsigned short* __restrict__ outb,
    float* __restrict__ sump,
    const int* __restrict__ go, const int* __restrict__ idx) {
  int b = blockIdx.y;
  if (!go[b]) return;
  int rg = blockIdx.x;
  int w = threadIdx.x >> 6, l = threadIdx.x & 63;
  int ix = idx[b];
  int d = l * 8;
  float gb8[8], gg[8], bb[8];
  {
    float4 a0 = *(const float4*)&gbias[ix * ND + d];
    float4 a1 = *(const float4*)&gbias[ix * ND + d + 4];
    gb8[0] = a0.x; gb8[1] = a0.y; gb8[2] = a0.z; gb8[3] = a0.w;
    gb8[4] = a1.x; gb8[5] = a1.y; gb8[6] = a1.z; gb8[7] = a1.w;
    float4 g0 = *(const float4*)&gall[ix * ND + d];
    float4 g1 = *(const float4*)&gall[ix * ND + d + 4];
    gg[0] = g0.x; gg[1] = g0.y; gg[2] = g0.z; gg[3] = g0.w;
    gg[4] = g1.x; gg[5] = g1.y; gg[6] = g1.z; gg[7] = g1.w;
    float4 b0 = *(const float4*)&beall[ix * ND + d];
    float4 b1 = *(const float4*)&beall[ix * ND + d + 4];
    bb[0] = b0.x; bb[1] = b0.y; bb[2] = b0.z; bb[3] = b0.w;
    bb[4] = b1.x; bb[5] = b1.y; bb[6] = b1.z; bb[7] = b1.w;
    if (TAG) {
      float4 t0 = *(const float4*)&tagall[ix * ND + d];
      float4 t1 = *(const float4*)&tagall[ix * ND + d + 4];
      bb[0] += t0.x; bb[1] += t0.y; bb[2] += t0.z; bb[3] += t0.w;
      bb[4] += t1.x; bb[5] += t1.y; bb[6] += t1.z; bb[7] += t1.w;
    }
  }
  float ps[8] = {0.f, 0.f, 0.f, 0.f, 0.f, 0.f, 0.f, 0.f};
  const size_t CSTRIDE = (size_t)NB * NS * ND;
  for (int rr = 0; rr < 4; ++rr) {
    int s = rg * 16 + w * 4 + rr;
    size_t base = ((size_t)b * NS + s) * ND;
    float4 x0 = *(const float4*)&res[base + d];
    float4 x1 = *(const float4*)&res[base + d + 4];
    float v[8] = {x0.x + gb8[0], x0.y + gb8[1], x0.z + gb8[2], x0.w + gb8[3],
                  x1.x + gb8[4], x1.y + gb8[5], x1.z + gb8[6], x1.w + gb8[7]};
#pragma unroll
    for (int c = 0; c < NCH; ++c) {
      const float* pc = part + c * CSTRIDE + base;
      float4 p0 = *(const float4*)&pc[d];
      float4 p1 = *(const float4*)&pc[d + 4];
      v[0] += p0.x; v[1] += p0.y; v[2] += p0.z; v[3] += p0.w;
      v[4] += p1.x; v[5] += p1.y; v[6] += p1.z; v[7] += p1.w;
    }
    float sum = 0.f;
#pragma unroll
    for (int j = 0; j < 8; ++j) sum += v[j];
#pragma unroll
    for (int off = 1; off < 64; off <<= 1) sum += __shfl_xor(sum, off);
    float mu = sum * (1.f / ND);
    float var = 0.f;
#pragma unroll
    for (int j = 0; j < 8; ++j) { v[j] -= mu; var += v[j] * v[j]; }
#pragma unroll
    for (int off = 1; off < 64; off <<= 1) var += __shfl_xor(var, off);
    float rs = rsqrtf(var * (1.f / ND) + 1e-5f);
    float o[8];
    short8 ob;
#pragma unroll
    for (int j = 0; j < 8; ++j) {
      o[j] = v[j] * rs * gg[j] + bb[j];
      if (SUMP) ps[j] += o[j];
      ob[j] = (short)f2bf(o[j]);
    }
    *(float4*)&outf[base + d] = (float4){o[0], o[1], o[2], o[3]};
    *(float4*)&outf[base + d + 4] = (float4){o[4], o[5], o[6], o[7]};
    *(short8*)&outb[base + d] = ob;
  }
  if (SUMP) {
    __shared__ float pl[4][ND];
#pragma unroll
    for (int j = 0; j < 8; ++j) pl[w][d + j] = ps[j];
    __syncthreads();
    if (w == 0) {
      float* pp = sump + ((size_t)b * 16 + rg) * ND;
#pragma unroll
      for (int j = 0; j < 8; ++j)
        pp[d + j] = pl[0][d + j] + pl[1][d + j] + pl[2][d + j] + pl[3][d + j];
    }
  }
}

// ---------------- LM head: 256x256-tile bf16 MFMA GEMM, 8 waves, counted-vmcnt depth-2 ----------------
__global__ __launch_bounds__(512, 2) void k_lmhead256(const unsigned short* __restrict__ Ab,
                                                      const unsigned short* __restrict__ Wb,
                                                      const float* __restrict__ bias,
                                                      float* __restrict__ out,
                                                      const float* __restrict__ entp) {
  if (blockIdx.x == 0 && threadIdx.x == 0)
    out[(size_t)NB * NS * NV] = *entp;  // fused k_ent
  int id = blockIdx.x;
  int swz = (id & 7) * 125 + (id >> 3);  // bijective: 1000 = 8 * 125
  int bm = (swz % 8) * 256;
  int bn = (swz / 8) * 256;

  __shared__ __align__(16) unsigned short As[2][256][32];
  __shared__ __align__(16) unsigned short Bs[2][256][32];
  int t = threadIdx.x;
  int lane = t & 63, w = t >> 6;
  int wm = (w >> 2) * 128, wn = (w & 3) * 64;
  f32x4 acc[8][4];
#pragma unroll
  for (int i = 0; i < 8; ++i)
#pragma unroll
    for (int j = 0; j < 4; ++j) acc[i][j] = (f32x4){0.f, 0.f, 0.f, 0.f};

  const unsigned short* ga = Ab + (size_t)(bm + w * 32 + (lane >> 2)) * ND + swzc(lane) * 8;
  const unsigned short* gb = Wb + (size_t)(bn + w * 32 + (lane >> 2)) * ND + swzc(lane) * 8;

#define ISSUEL(slot, kt)                                           \
  gload16(ga + (kt) * 32, &As[slot][w * 32][0]);                   \
  gload16(ga + (kt) * 32 + 16 * ND, &As[slot][w * 32 + 16][0]);    \
  gload16(gb + (kt) * 32, &Bs[slot][w * 32][0]);                   \
  gload16(gb + (kt) * 32 + 16 * ND, &Bs[slot][w * 32 + 16][0]);

  ISSUEL(0, 0)
  ISSUEL(1, 1)

  int row0 = lane & 15;
  int cs = ((lane >> 4) ^ ((row0 >> 1) & 3)) * 8;
  for (int it = 0; it < 16; ++it) {
    if (it < 15) asm volatile("s_waitcnt vmcnt(4)" ::: "memory");
    else         asm volatile("s_waitcnt vmcnt(0)" ::: "memory");
    asm volatile("s_barrier" ::: "memory");  // tile it landed for all waves
    int sl = it & 1;
    short8 a[8], bfr[4];
#pragma unroll
    for (int mf = 0; mf < 8; ++mf)
      a[mf] = *(const short8*)&As[sl][wm + mf * 16 + row0][cs];
#pragma unroll
    for (int nf = 0; nf < 4; ++nf)
      bfr[nf] = *(const short8*)&Bs[sl][wn + nf * 16 + row0][cs];
    __builtin_amdgcn_s_setprio(1);
#pragma unroll
    for (int mf = 0; mf < 8; ++mf)
#pragma unroll
      for (int nf = 0; nf < 4; ++nf)
        acc[mf][nf] = __builtin_amdgcn_mfma_f32_16x16x32_bf16(a[mf], bfr[nf], acc[mf][nf], 0, 0, 0);
    __builtin_amdgcn_s_setprio(0);
    asm volatile("s_barrier" ::: "memory");  // reads of slot sl done
    if (it + 2 < 16) { ISSUEL(sl, it + 2) }
  }
#undef ISSUEL

  int lrow = (lane >> 4) * 4, lcol = lane & 15;
#pragma unroll
  for (int nf = 0; nf < 4; ++nf) {
    int col = bn + wn + nf * 16 + lcol;
    float bv = bias[col];
#pragma unroll
    for (int mf = 0; mf < 8; ++mf) {
#pragma unroll
      for (int r = 0; r < 4; ++r) {
        int row = bm + wm + mf * 16 + lrow + r;
        out[(size_t)row * NV + col] = acc[mf][nf][r] + bv;
      }
    }
  }
}

extern "C" void kernel_launch(void* const* d_in, const int* in_sizes, int n_in,
                              void* d_out, int out_size, void* d_ws, size_t ws_size,
                              hipStream_t stream) {
  const int* ids   = (const int*)d_in[0];
  const float* emb = (const float*)d_in[1];
  const float* pe  = (const float*)d_in[2];
  const float* Wqkv = (const float*)d_in[3];
  const float* bqkv = (const float*)d_in[4];
  const float* Wo   = (const float*)d_in[5];
  const float* bo   = (const float*)d_in[6];
  const float* W1   = (const float*)d_in[7];
  const float* b1   = (const float*)d_in[8];
  const float* W2   = (const float*)d_in[9];
  const float* b2   = (const float*)d_in[10];
  const float* g1   = (const float*)d_in[11];
  const float* be1  = (const float*)d_in[12];
  const float* g2   = (const float*)d_in[13];
  const float* be2  = (const float*)d_in[14];
  const float* tag  = (const float*)d_in[15];
  const float* rw1  = (const float*)d_in[16];
  const float* rb1  = (const float*)d_in[17];
  const float* rw2  = (const float*)d_in[18];
  const float* rb2  = (const float*)d_in[19];
  const float* lmw  = (const float*)d_in[20];
  const float* lmb  = (const float*)d_in[21];
  float* out = (float*)d_out;

  float* ws = (float*)d_ws;
  size_t o = 0;
  float* rep = ws + o;  o += (size_t)NB * NS * ND;           // fp32
  float* x1  = ws + o;  o += (size_t)NB * NS * ND;
  float* partk = ws + o; o += (size_t)4 * NB * NS * ND;       // split-K partials
  float* partial = ws + o; o += (size_t)NB * 16 * ND;         // summary partials
  int* visits = (int*)(ws + o); o += 1024;
  int* active = visits + NB * NE;
  int* idx = active + NB;
  int* go = idx + NB;
  float* entp = (float*)(go + NB);

  unsigned short* us = (unsigned short*)(ws + o);
  size_t uo = 0;
  unsigned short* rep_b = us + uo; uo += (size_t)NB * NS * ND;
  unsigned short* x1_b  = us + uo; uo += (size_t)NB * NS * ND;
  unsigned short* ctx_b = us + uo; uo += (size_t)NB * NS * ND;
  unsigned short* Qb    = us + uo; uo += (size_t)NB * NS * ND;
  unsigned short* Kb    = us + uo; uo += (size_t)NB * NS * ND;
  unsigned short* Vt    = us + uo; uo += (size_t)NB * NS * ND;
  unsigned short* hid_b = us + uo; uo += (size_t)NB * NS * NFF;
  unsigned short* Wqkv_b = us + uo; uo += (size_t)NE * 3 * ND * ND;
  unsigned short* Wo_b   = us + uo; uo += (size_t)NE * ND * ND;
  unsigned short* W1_b   = us + uo; uo += (size_t)NE * NFF * ND;
  unsigned short* W2_b   = us + uo; uo += (size_t)NE * ND * NFF;
  unsigned short* lmw_b  = us + uo; uo += (size_t)NV * ND;

  // fused weight pre-casts + state init + embedding (deterministic every call)
  {
    int n0 = NE * 3 * ND * ND / 8, n1 = NE * ND * ND / 8, n2 = NE * NFF * ND / 8,
        n3 = NE * ND * NFF / 8, n4 = NV * ND / 8;
    int nbcast = (n0 + n1 + n2 + n3 + n4) / 256;
    k_cast5e<<<nbcast + 16 * NB, 256, 0, stream>>>(
        Wqkv, Wqkv_b, n0, Wo, Wo_b, n1, W1, W1_b, n2, W2, W2_b, n3, lmw, lmw_b, n4,
        nbcast, ids, emb, pe, rep, rep_b, partial, visits, active, entp);
  }

  for (int step = 0; step < 4; ++step) {
    k_router<<<1, 256, 0, stream>>>(partial, rw1, rb1, rw2, rb2,
                                    visits, active, idx, go, entp);
    // qkv: rep_b @ Wqkv^T + bqkv -> Qb/Kb bf16, Vt transposed (768 blocks)
    k_gemm64p<2, 0, 1><<<dim3(4, 24, NB), 256, 0, stream>>>(
        rep_b, NS * ND, Wqkv_b, bqkv, nullptr, nullptr, 0, 3 * ND, ND,
        Qb, Kb, Vt, go, idx);
    // attention (staged K/V, P overlay)
    k_attn2<<<dim3(4, NH, NB), 256, 0, stream>>>(Qb, Kb, Vt, ctx_b, go);
    // wo: ctx @ Wo^T -> 2-way split-K partials (512 blocks)
    k_gemm64p<0, 0, 2><<<dim3(8, 8, NB), 256, 0, stream>>>(
        ctx_b, NS * ND, Wo_b, nullptr, partk, nullptr, 0, ND, ND,
        nullptr, nullptr, nullptr, go, idx);
    // x1 = LN(rep + sum(partials) + bo)
    k_ln_red<2, 0, 0><<<dim3(16, NB), 256, 0, stream>>>(
        rep, partk, bo, g1, be1, nullptr, x1, x1_b, nullptr, go, idx);
    // hid = relu(x1 @ W1^T + b1) -> bf16 (1024 blocks)
    k_gemm64p<1, 1, 1><<<dim3(4, 32, NB), 256, 0, stream>>>(
        x1_b, NS * ND, W1_b, b1, nullptr, hid_b, NS * NFF, NFF, ND,
        nullptr, nullptr, nullptr, go, idx);
    // w2: hid @ W2^T -> 4-way split-K partials (1024 blocks)
    k_gemm64p<0, 0, 4><<<dim3(16, 8, NB), 256, 0, stream>>>(
        hid_b, NS * NFF, W2_b, nullptr, partk, nullptr, 0, ND, NFF,
        nullptr, nullptr, nullptr, go, idx);
    // rep = LN(x1 + sum(partials) + b2) + tag, + 16-row summary partials
    k_ln_red<4, 1, 1><<<dim3(16, NB), 256, 0, stream>>>(
        x1, partk, b2, g2, be2, tag, rep, rep_b, partial, go, idx);
  }

  k_lmhead256<<<1000, 512, 0, stream>>>(rep_b, lmw_b, lmb, out, entp);
}

// Round 14
// 507.007 us; speedup vs baseline: 1.1743x; 1.1642x over previous
//
#include <hip/hip_runtime.h>
#include <hip/hip_bf16.h>

#define NB 8
#define NS 256
#define ND 512
#define NH 8
#define NDH 64
#define NFF 2048
#define NE 8
#define NV 32000
#define NRH 256
#define MAXV 2
#define NEGV (-1e9f)

typedef __attribute__((ext_vector_type(8))) short short8;
typedef __attribute__((ext_vector_type(4))) float f32x4;

__device__ __forceinline__ unsigned short f2bf(float x) {
  unsigned int u = __float_as_uint(x);
  u = (u + 0x7fffu + ((u >> 16) & 1u)) >> 16;
  return (unsigned short)u;
}

// async global->LDS, 16 bytes per lane; LDS dest is wave-uniform base + lane*16
__device__ __forceinline__ void gload16(const unsigned short* g, unsigned short* l) {
  __builtin_amdgcn_global_load_lds(
      (const __attribute__((address_space(1))) unsigned int*)g,
      (__attribute__((address_space(3))) unsigned int*)l, 16, 0, 0);
}

// 32-col-row staging swizzle (lmhead): lane -> chunk (l&3) ^ ((l>>3)&3)
__device__ __forceinline__ int swzc(int lane) {
  return (lane & 3) ^ ((lane >> 3) & 3);
}

// ---------------- fused: weight casts + state init + embedding ----------------
__device__ __forceinline__ void cast8(const float* s, unsigned short* d, int j) {
  const float4* s4 = (const float4*)s;
  float4 a = s4[j * 2], b = s4[j * 2 + 1];
  short8 v;
  v[0] = (short)f2bf(a.x); v[1] = (short)f2bf(a.y);
  v[2] = (short)f2bf(a.z); v[3] = (short)f2bf(a.w);
  v[4] = (short)f2bf(b.x); v[5] = (short)f2bf(b.y);
  v[6] = (short)f2bf(b.z); v[7] = (short)f2bf(b.w);
  *(short8*)&d[(size_t)j * 8] = v;
}

__global__ __launch_bounds__(256) void k_cast5e(
    const float* s0, unsigned short* d0, int n0,
    const float* s1, unsigned short* d1, int n1,
    const float* s2, unsigned short* d2, int n2,
    const float* s3, unsigned short* d3, int n3,
    const float* s4, unsigned short* d4, int n4,
    int nbcast,
    const int* __restrict__ ids, const float* __restrict__ emb,
    const float* __restrict__ pe, float* __restrict__ rep,
    unsigned short* __restrict__ repb, float* __restrict__ partial,
    int* visits, int* active, float* entp) {
  if (blockIdx.x == 0) {
    if (threadIdx.x < NB * NE) visits[threadIdx.x] = 0;
    if (threadIdx.x < NB) active[threadIdx.x] = 1;
    if (threadIdx.x == 0) *entp = 0.f;
  }
  if ((int)blockIdx.x >= nbcast) {
    int j2 = blockIdx.x - nbcast;
    int rg = j2 & 15, b = j2 >> 4;
    int t = threadIdx.x;
    int c0 = t, c1 = t + 256;
    float pa0 = 0.f, pa1 = 0.f, pb0 = 0.f, pb1 = 0.f;
    for (int row = 0; row < 16; ++row) {
      int s = rg * 16 + row;
      int id = ids[b * NS + s];
      float sc = (id != 0) ? 22.627416997969522f : 0.f;  // sqrt(512), pad row zeroed
      float v0 = emb[(size_t)id * ND + c0] * sc + pe[(size_t)s * ND + c0];
      float v1 = emb[(size_t)id * ND + c1] * sc + pe[(size_t)s * ND + c1];
      size_t base = ((size_t)b * NS + s) * ND;
      rep[base + c0] = v0; rep[base + c1] = v1;
      repb[base + c0] = f2bf(v0); repb[base + c1] = f2bf(v1);
      if (row < 8) { pa0 += v0; pa1 += v1; } else { pb0 += v0; pb1 += v1; }
    }
    // partial: 32 groups of 8 rows per batch
    float* ppa = partial + ((size_t)b * 32 + rg * 2) * ND;
    float* ppb = ppa + ND;
    ppa[c0] = pa0; ppa[c1] = pa1;
    ppb[c0] = pb0; ppb[c1] = pb1;
    return;
  }
  int j = blockIdx.x * 256 + threadIdx.x;
  if (j < n0) { cast8(s0, d0, j); return; }
  j -= n0;
  if (j < n1) { cast8(s1, d1, j); return; }
  j -= n1;
  if (j < n2) { cast8(s2, d2, j); return; }
  j -= n2;
  if (j < n3) { cast8(s3, d3, j); return; }
  j -= n3;
  if (j < n4) cast8(s4, d4, j);
}

// ---------------- router: one block per batch; active ping-pong; ent via atomicAdd ----------------
__global__ __launch_bounds__(256) void k_router8(
    const float* __restrict__ partial,
    const float* __restrict__ rw1, const float* __restrict__ rb1,
    const float* __restrict__ rw2, const float* __restrict__ rb2,
    int* visits, const int* __restrict__ active_in, int* active_out,
    int* idx, int* go, float* ent_total) {
  int b = blockIdx.x;
  __shared__ float sm[ND];
  __shared__ float h[NRH];
  __shared__ float lg[NE + 1];
  __shared__ int scnt;
  int t = threadIdx.x;
  for (int i = t; i < ND; i += 256) {
    const float* pp = partial + ((size_t)b * 32) * ND + i;
    float s = 0.f;
#pragma unroll
    for (int rg = 0; rg < 32; ++rg) s += pp[(size_t)rg * ND];
    sm[i] = s * (1.f / NS);
  }
  if (t == 0) {
    int c = 0;
    for (int bb = 0; bb < NB; ++bb) c += active_in[bb];
    scnt = c;
  }
  __syncthreads();
  {
    const float* w = rw1 + (size_t)t * ND;
    float acc = rb1[t];
    for (int d = 0; d < ND; ++d) acc += sm[d] * w[d];
    h[t] = fmaxf(acc, 0.f);
  }
  __syncthreads();
  if (t < NE + 1) {
    const float* w = rw2 + t * NRH;
    float a = rb2[t];
    for (int r = 0; r < NRH; ++r) a += h[r] * w[r];
    lg[t] = a;
  }
  __syncthreads();
  if (t == 0) {
    int aprev = active_in[b];
    float l[NE + 1];
    for (int e = 0; e < NE; ++e)
      l[e] = (visits[b * NE + e] >= MAXV) ? NEGV : lg[e];
    l[NE] = lg[NE];
    float m = l[0];
    for (int e = 1; e <= NE; ++e) m = fmaxf(m, l[e]);
    float z = 0.f, p[NE + 1];
    for (int e = 0; e <= NE; ++e) { p[e] = __expf(l[e] - m); z += p[e]; }
    float zi = 1.f / z, ent = 0.f;
    for (int e = 0; e <= NE; ++e) {
      float pp = p[e] * zi;
      ent -= pp * __logf(pp + 1e-9f);
    }
    if (aprev && scnt > 0) atomicAdd(ent_total, ent / (float)scnt);
    int ch = 0; float bm = l[0];
    for (int e = 1; e <= NE; ++e) if (l[e] > bm) { bm = l[e]; ch = e; }
    int g = (aprev && ch < NE) ? 1 : 0;
    int ix = g ? ch : 0;
    visits[b * NE + ix] += g;
    idx[b] = ix; go[b] = g; active_out[b] = g;
  }
}

// ---------------- 64x64-tile bf16 MFMA expert GEMM, BK=64, depth-2 counted-vmcnt ----------------
// OUT: 0 = fp32 split-K partials (no bias), 1 = bf16 + bias (+relu), 2 = qkv-split.
// SK = split-K ways. grid (4*SK, N/64, NB). Fully gated.
template <int OUT, int RELU, int SK>
__global__ __launch_bounds__(256) void k_gemm64p(
    const unsigned short* __restrict__ Aall, int sa,
    const unsigned short* __restrict__ Wall, const float* __restrict__ ball,
    float* __restrict__ Pall, unsigned short* __restrict__ Uall, int so,
    int N, int K,
    unsigned short* __restrict__ Qb, unsigned short* __restrict__ Kb,
    unsigned short* __restrict__ Vt,
    const int* __restrict__ go, const int* __restrict__ idx) {
  int b = blockIdx.z;
  if (!go[b]) return;
  int t = threadIdx.x;
  int lane = t & 63, w = t >> 6;
  int wm = (w >> 1) * 32, wn = (w & 1) * 32;
  int kc = blockIdx.x >> 2;
  int bm = (blockIdx.x & 3) * 64, bn = blockIdx.y * 64;
  int KC = K / SK;
  int lrow = (lane >> 4) * 4, lcol = lane & 15;
  const unsigned short* A = Aall + (size_t)b * sa + kc * KC;
  const unsigned short* W = Wall + (size_t)idx[b] * N * K + kc * KC;

  __shared__ __align__(16) unsigned short As[2][64][64];  // 16 KB
  __shared__ __align__(16) unsigned short Bs[2][64][64];  // 16 KB
  f32x4 acc[2][2];
#pragma unroll
  for (int i = 0; i < 2; ++i)
#pragma unroll
    for (int j = 0; j < 2; ++j) acc[i][j] = (f32x4){0.f, 0.f, 0.f, 0.f};

  // wave w stages rows [w*16, w*16+16); lane l -> row (l>>3), chunk (l&7)^((l>>3)&7)
  int ch8 = (lane & 7) ^ ((lane >> 3) & 7);
  const unsigned short* ga = A + (size_t)(bm + w * 16 + (lane >> 3)) * K + ch8 * 8;
  const unsigned short* gb = W + (size_t)(bn + w * 16 + (lane >> 3)) * K + ch8 * 8;

#define ISSUE64(slot, kt)                                            \
  gload16(ga + (size_t)(kt) * 64, &As[slot][w * 16][0]);             \
  gload16(ga + (size_t)(kt) * 64 + 8 * (size_t)K, &As[slot][w * 16 + 8][0]); \
  gload16(gb + (size_t)(kt) * 64, &Bs[slot][w * 16][0]);             \
  gload16(gb + (size_t)(kt) * 64 + 8 * (size_t)K, &Bs[slot][w * 16 + 8][0]);

  int nk = KC >> 6;  // >= 4 for all uses
  ISSUE64(0, 0)
  ISSUE64(1, 1)

  int row0 = lane & 15, g = lane >> 4;
  for (int it = 0; it < nk; ++it) {
    if (it < nk - 1) asm volatile("s_waitcnt vmcnt(4)" ::: "memory");
    else             asm volatile("s_waitcnt vmcnt(0)" ::: "memory");
    asm volatile("s_barrier" ::: "memory");  // all waves: tile it landed
    int sl = it & 1;
    __builtin_amdgcn_s_setprio(1);
#pragma unroll
    for (int kk = 0; kk < 2; ++kk) {
      int co = ((kk * 4 + g) ^ (row0 & 7)) * 8;
      short8 a0 = *(const short8*)&As[sl][wm + row0][co];
      short8 a1 = *(const short8*)&As[sl][wm + 16 + row0][co];
      short8 b0 = *(const short8*)&Bs[sl][wn + row0][co];
      short8 b1 = *(const short8*)&Bs[sl][wn + 16 + row0][co];
      acc[0][0] = __builtin_amdgcn_mfma_f32_16x16x32_bf16(a0, b0, acc[0][0], 0, 0, 0);
      acc[0][1] = __builtin_amdgcn_mfma_f32_16x16x32_bf16(a0, b1, acc[0][1], 0, 0, 0);
      acc[1][0] = __builtin_amdgcn_mfma_f32_16x16x32_bf16(a1, b0, acc[1][0], 0, 0, 0);
      acc[1][1] = __builtin_amdgcn_mfma_f32_16x16x32_bf16(a1, b1, acc[1][1], 0, 0, 0);
    }
    __builtin_amdgcn_s_setprio(0);
    asm volatile("s_barrier" ::: "memory");  // all waves done reading slot sl
    if (it + 2 < nk) { ISSUE64(sl, it + 2) }
  }
#undef ISSUE64

  if (OUT == 2) {
    const float* bias = ball + (size_t)idx[b] * N;
    int seg = bn >> 9;  // 0:Q 1:K 2:V — 64-tile never crosses a 512 boundary
#pragma unroll
    for (int nf = 0; nf < 2; ++nf) {
      int col = bn + wn + nf * 16 + lcol;
      float bv = bias[col];
      if (seg < 2) {
        unsigned short* dst = (seg == 0) ? Qb : Kb;
        int cc = col - seg * 512;
#pragma unroll
        for (int mf = 0; mf < 2; ++mf)
#pragma unroll
          for (int r = 0; r < 4; ++r) {
            int row = bm + wm + mf * 16 + lrow + r;
            dst[((size_t)b * NS + row) * ND + cc] = f2bf(acc[mf][nf][r] + bv);
          }
      } else {
        int dcol = col - 1024;
#pragma unroll
        for (int mf = 0; mf < 2; ++mf) {
          int s0 = bm + wm + mf * 16 + lrow;
          unsigned long long pk =
              (unsigned long long)f2bf(acc[mf][nf][0] + bv) |
              ((unsigned long long)f2bf(acc[mf][nf][1] + bv) << 16) |
              ((unsigned long long)f2bf(acc[mf][nf][2] + bv) << 32) |
              ((unsigned long long)f2bf(acc[mf][nf][3] + bv) << 48);
          *(unsigned long long*)&Vt[((size_t)b * 512 + dcol) * 256 + s0] = pk;
        }
      }
    }
  } else if (OUT == 1) {
    const float* bias = ball + (size_t)idx[b] * N;
#pragma unroll
    for (int nf = 0; nf < 2; ++nf) {
      int col = bn + wn + nf * 16 + lcol;
      float bv = bias[col];
#pragma unroll
      for (int mf = 0; mf < 2; ++mf) {
#pragma unroll
        for (int r = 0; r < 4; ++r) {
          int row = bm + wm + mf * 16 + lrow + r;
          float v = acc[mf][nf][r] + bv;
          if (RELU) v = fmaxf(v, 0.f);
          Uall[(size_t)b * so + (size_t)row * N + col] = f2bf(v);
        }
      }
    }
  } else {
    float* P = Pall + ((size_t)kc * NB + b) * ((size_t)NS * N);
#pragma unroll
    for (int nf = 0; nf < 2; ++nf) {
      int col = bn + wn + nf * 16 + lcol;
#pragma unroll
      for (int mf = 0; mf < 2; ++mf)
#pragma unroll
        for (int r = 0; r < 4; ++r)
          P[(size_t)(bm + wm + mf * 16 + lrow + r) * N + col] = acc[mf][nf][r];
    }
  }
}

// ---------------- MFMA flash attention, staged K/V ----------------
__global__ __launch_bounds__(256) void k_attn2(const unsigned short* __restrict__ Qb,
                                               const unsigned short* __restrict__ Kb,
                                               const unsigned short* __restrict__ Vt,
                                               unsigned short* __restrict__ ctxb,
                                               const int* __restrict__ go) {
  int b = blockIdx.z, h = blockIdx.y, qt = blockIdx.x;
  if (!go[b]) return;  // ctx_b consumers are gated
  int t = threadIdx.x;
  __shared__ __align__(16) unsigned short lds0[16384];  // K then P
  __shared__ __align__(16) unsigned short lds1[16384];  // V^T
  int lane = t & 63, w = t >> 6, g = lane >> 4, c = lane & 15;

#pragma unroll
  for (int i = 0; i < 8; ++i) {
    int task = i * 256 + t;
    int k = task >> 3, cc = task & 7;
    short8 v = *(const short8*)&Kb[((size_t)b * NS + k) * ND + h * NDH + cc * 8];
    *(short8*)&lds0[k * 64 + ((cc * 8) ^ ((k & 7) << 3))] = v;
  }
#pragma unroll
  for (int i = 0; i < 8; ++i) {
    int task = i * 256 + t;
    int d = task >> 5, kc = task & 31;
    short8 v = *(const short8*)&Vt[((size_t)b * 512 + h * NDH + d) * 256 + kc * 8];
    *(short8*)&lds1[d * 256 + ((kc * 8) ^ ((d & 7) << 3))] = v;
  }
  short8 qf[2];
  {
    const unsigned short* qp = Qb + ((size_t)b * NS + qt * 64 + w * 16 + c) * ND + h * NDH;
    qf[0] = *(const short8*)&qp[g * 8];
    qf[1] = *(const short8*)&qp[32 + g * 8];
  }
  __syncthreads();

  f32x4 sacc[16];
#pragma unroll
  for (int mf = 0; mf < 16; ++mf) sacc[mf] = (f32x4){0.f, 0.f, 0.f, 0.f};
#pragma unroll
  for (int mf = 0; mf < 16; ++mf) {
#pragma unroll
    for (int kd = 0; kd < 2; ++kd) {
      int row = mf * 16 + c;
      short8 kf = *(const short8*)&lds0[row * 64 + ((kd * 32 + g * 8) ^ ((row & 7) << 3))];
      sacc[mf] = __builtin_amdgcn_mfma_f32_16x16x32_bf16(kf, qf[kd], sacc[mf], 0, 0, 0);
    }
  }
  __syncthreads();  // lds0 becomes P

  float mx = -3.4e38f;
#pragma unroll
  for (int mf = 0; mf < 16; ++mf) {
#pragma unroll
    for (int r = 0; r < 4; ++r) {
      sacc[mf][r] *= 0.125f;
      mx = fmaxf(mx, sacc[mf][r]);
    }
  }
  mx = fmaxf(mx, __shfl_xor(mx, 16));
  mx = fmaxf(mx, __shfl_xor(mx, 32));
  float sum = 0.f;
#pragma unroll
  for (int mf = 0; mf < 16; ++mf)
#pragma unroll
    for (int r = 0; r < 4; ++r) {
      float p = __expf(sacc[mf][r] - mx);
      sacc[mf][r] = p;
      sum += p;
    }
  sum += __shfl_xor(sum, 16);
  sum += __shfl_xor(sum, 32);
  float zi = 1.f / sum;

  int q_l = w * 16 + c;
#pragma unroll
  for (int mf = 0; mf < 16; ++mf) {
    unsigned long long pk =
        (unsigned long long)f2bf(sacc[mf][0] * zi) |
        ((unsigned long long)f2bf(sacc[mf][1] * zi) << 16) |
        ((unsigned long long)f2bf(sacc[mf][2] * zi) << 32) |
        ((unsigned long long)f2bf(sacc[mf][3] * zi) << 48);
    *(unsigned long long*)&lds0[q_l * 256 + ((mf * 16 + g * 4) ^ ((q_l & 7) << 3))] = pk;
  }

  f32x4 cacc[4];
#pragma unroll
  for (int nf = 0; nf < 4; ++nf) cacc[nf] = (f32x4){0.f, 0.f, 0.f, 0.f};
#pragma unroll
  for (int ks = 0; ks < 8; ++ks) {
    int prow = w * 16 + c;
    short8 pf = *(const short8*)&lds0[prow * 256 + ((ks * 32 + g * 8) ^ ((prow & 7) << 3))];
#pragma unroll
    for (int nf = 0; nf < 4; ++nf) {
      int vrow = nf * 16 + c;
      short8 vf = *(const short8*)&lds1[vrow * 256 + ((ks * 32 + g * 8) ^ ((vrow & 7) << 3))];
      cacc[nf] = __builtin_amdgcn_mfma_f32_16x16x32_bf16(pf, vf, cacc[nf], 0, 0, 0);
    }
  }
#pragma unroll
  for (int nf = 0; nf < 4; ++nf)
#pragma unroll
    for (int r = 0; r < 4; ++r)
      ctxb[((size_t)b * NS + qt * 64 + w * 16 + g * 4 + r) * ND + h * NDH + nf * 16 + c] =
          f2bf(cacc[nf][r]);
}

// ---------------- partial-reduce + GEMM bias + residual + LayerNorm (+tag, +summary) ----------------
// 8 rows/block, grid (32, NB). Gated. part = [NCH][NB][NS][ND] fp32 split-K partials.
template <int NCH, int TAG, int SUMP>
__global__ __launch_bounds__(256) void k_ln_red(
    const float* __restrict__ res, const float* __restrict__ part,
    const float* __restrict__ gbias,
    const float* __restrict__ gall, const float* __restrict__ beall,
    const float* __restrict__ tagall,
    float* __restrict__ outf, unsigned short* __restrict__ outb,
    float* __restrict__ sump,
    const int* __restrict__ go, const int* __restrict__ idx) {
  int b = blockIdx.y;
  if (!go[b]) return;
  int rg = blockIdx.x;  // 0..31, 8 rows each
  int w = threadIdx.x >> 6, l = threadIdx.x & 63;
  int ix = idx[b];
  int d = l * 8;
  float gb8[8], gg[8], bb[8];
  {
    float4 a0 = *(const float4*)&gbias[ix * ND + d];
    float4 a1 = *(const float4*)&gbias[ix * ND + d + 4];
    gb8[0] = a0.x; gb8[1] = a0.y; gb8[2] = a0.z; gb8[3] = a0.w;
    gb8[4] = a1.x; gb8[5] = a1.y; gb8[6] = a1.z; gb8[7] = a1.w;
    float4 g0 = *(const float4*)&gall[ix * ND + d];
    float4 g1 = *(const float4*)&gall[ix * ND + d + 4];
    gg[0] = g0.x; gg[1] = g0.y; gg[2] = g0.z; gg[3] = g0.w;
    gg[4] = g1.x; gg[5] = g1.y; gg[6] = g1.z; gg[7] = g1.w;
    float4 b0 = *(const float4*)&beall[ix * ND + d];
    float4 b1 = *(const float4*)&beall[ix * ND + d + 4];
    bb[0] = b0.x; bb[1] = b0.y; bb[2] = b0.z; bb[3] = b0.w;
    bb[4] = b1.x; bb[5] = b1.y; bb[6] = b1.z; bb[7] = b1.w;
    if (TAG) {
      float4 t0 = *(const float4*)&tagall[ix * ND + d];
      float4 t1 = *(const float4*)&tagall[ix * ND + d + 4];
      bb[0] += t0.x; bb[1] += t0.y; bb[2] += t0.z; bb[3] += t0.w;
      bb[4] += t1.x; bb[5] += t1.y; bb[6] += t1.z; bb[7] += t1.w;
    }
  }
  float ps[8] = {0.f, 0.f, 0.f, 0.f, 0.f, 0.f, 0.f, 0.f};
  const size_t CSTRIDE = (size_t)NB * NS * ND;
  for (int rr = 0; rr < 2; ++rr) {
    int s = rg * 8 + w * 2 + rr;
    size_t base = ((size_t)b * NS + s) * ND;
    float4 x0 = *(const float4*)&res[base + d];
    float4 x1 = *(const float4*)&res[base + d + 4];
    float v[8] = {x0.x + gb8[0], x0.y + gb8[1], x0.z + gb8[2], x0.w + gb8[3],
                  x1.x + gb8[4], x1.y + gb8[5], x1.z + gb8[6], x1.w + gb8[7]};
#pragma unroll
    for (int c = 0; c < NCH; ++c) {
      const float* pc = part + c * CSTRIDE + base;
      float4 p0 = *(const float4*)&pc[d];
      float4 p1 = *(const float4*)&pc[d + 4];
      v[0] += p0.x; v[1] += p0.y; v[2] += p0.z; v[3] += p0.w;
      v[4] += p1.x; v[5] += p1.y; v[6] += p1.z; v[7] += p1.w;
    }
    float sum = 0.f;
#pragma unroll
    for (int j = 0; j < 8; ++j) sum += v[j];
#pragma unroll
    for (int off = 1; off < 64; off <<= 1) sum += __shfl_xor(sum, off);
    float mu = sum * (1.f / ND);
    float var = 0.f;
#pragma unroll
    for (int j = 0; j < 8; ++j) { v[j] -= mu; var += v[j] * v[j]; }
#pragma unroll
    for (int off = 1; off < 64; off <<= 1) var += __shfl_xor(var, off);
    float rs = rsqrtf(var * (1.f / ND) + 1e-5f);
    float o[8];
    short8 ob;
#pragma unroll
    for (int j = 0; j < 8; ++j) {
      o[j] = v[j] * rs * gg[j] + bb[j];
      if (SUMP) ps[j] += o[j];
      ob[j] = (short)f2bf(o[j]);
    }
    *(float4*)&outf[base + d] = (float4){o[0], o[1], o[2], o[3]};
    *(float4*)&outf[base + d + 4] = (float4){o[4], o[5], o[6], o[7]};
    *(short8*)&outb[base + d] = ob;
  }
  if (SUMP) {
    __shared__ float pl[4][ND];
#pragma unroll
    for (int j = 0; j < 8; ++j) pl[w][d + j] = ps[j];
    __syncthreads();
    if (w == 0) {
      float* pp = sump + ((size_t)b * 32 + rg) * ND;
#pragma unroll
      for (int j = 0; j < 8; ++j)
        pp[d + j] = pl[0][d + j] + pl[1][d + j] + pl[2][d + j] + pl[3][d + j];
    }
  }
}

// ---------------- LM head: 256x256-tile bf16 MFMA GEMM, 8 waves, counted-vmcnt depth-2 ----------------
__global__ __launch_bounds__(512, 2) void k_lmhead256(const unsigned short* __restrict__ Ab,
                                                      const unsigned short* __restrict__ Wb,
                                                      const float* __restrict__ bias,
                                                      float* __restrict__ out,
                                                      const float* __restrict__ entp) {
  if (blockIdx.x == 0 && threadIdx.x == 0)
    out[(size_t)NB * NS * NV] = *entp;  // fused k_ent
  int id = blockIdx.x;
  int swz = (id & 7) * 125 + (id >> 3);  // bijective: 1000 = 8 * 125
  int bm = (swz % 8) * 256;
  int bn = (swz / 8) * 256;

  __shared__ __align__(16) unsigned short As[2][256][32];
  __shared__ __align__(16) unsigned short Bs[2][256][32];
  int t = threadIdx.x;
  int lane = t & 63, w = t >> 6;
  int wm = (w >> 2) * 128, wn = (w & 3) * 64;
  f32x4 acc[8][4];
#pragma unroll
  for (int i = 0; i < 8; ++i)
#pragma unroll
    for (int j = 0; j < 4; ++j) acc[i][j] = (f32x4){0.f, 0.f, 0.f, 0.f};

  const unsigned short* ga = Ab + (size_t)(bm + w * 32 + (lane >> 2)) * ND + swzc(lane) * 8;
  const unsigned short* gb = Wb + (size_t)(bn + w * 32 + (lane >> 2)) * ND + swzc(lane) * 8;

#define ISSUEL(slot, kt)                                           \
  gload16(ga + (kt) * 32, &As[slot][w * 32][0]);                   \
  gload16(ga + (kt) * 32 + 16 * ND, &As[slot][w * 32 + 16][0]);    \
  gload16(gb + (kt) * 32, &Bs[slot][w * 32][0]);                   \
  gload16(gb + (kt) * 32 + 16 * ND, &Bs[slot][w * 32 + 16][0]);

  ISSUEL(0, 0)
  ISSUEL(1, 1)

  int row0 = lane & 15;
  int cs = ((lane >> 4) ^ ((row0 >> 1) & 3)) * 8;
  for (int it = 0; it < 16; ++it) {
    if (it < 15) asm volatile("s_waitcnt vmcnt(4)" ::: "memory");
    else         asm volatile("s_waitcnt vmcnt(0)" ::: "memory");
    asm volatile("s_barrier" ::: "memory");  // tile it landed for all waves
    int sl = it & 1;
    short8 a[8], bfr[4];
#pragma unroll
    for (int mf = 0; mf < 8; ++mf)
      a[mf] = *(const short8*)&As[sl][wm + mf * 16 + row0][cs];
#pragma unroll
    for (int nf = 0; nf < 4; ++nf)
      bfr[nf] = *(const short8*)&Bs[sl][wn + nf * 16 + row0][cs];
    __builtin_amdgcn_s_setprio(1);
#pragma unroll
    for (int mf = 0; mf < 8; ++mf)
#pragma unroll
      for (int nf = 0; nf < 4; ++nf)
        acc[mf][nf] = __builtin_amdgcn_mfma_f32_16x16x32_bf16(a[mf], bfr[nf], acc[mf][nf], 0, 0, 0);
    __builtin_amdgcn_s_setprio(0);
    asm volatile("s_barrier" ::: "memory");  // reads of slot sl done
    if (it + 2 < 16) { ISSUEL(sl, it + 2) }
  }
#undef ISSUEL

  int lrow = (lane >> 4) * 4, lcol = lane & 15;
#pragma unroll
  for (int nf = 0; nf < 4; ++nf) {
    int col = bn + wn + nf * 16 + lcol;
    float bv = bias[col];
#pragma unroll
    for (int mf = 0; mf < 8; ++mf) {
#pragma unroll
      for (int r = 0; r < 4; ++r) {
        int row = bm + wm + mf * 16 + lrow + r;
        out[(size_t)row * NV + col] = acc[mf][nf][r] + bv;
      }
    }
  }
}

extern "C" void kernel_launch(void* const* d_in, const int* in_sizes, int n_in,
                              void* d_out, int out_size, void* d_ws, size_t ws_size,
                              hipStream_t stream) {
  const int* ids   = (const int*)d_in[0];
  const float* emb = (const float*)d_in[1];
  const float* pe  = (const float*)d_in[2];
  const float* Wqkv = (const float*)d_in[3];
  const float* bqkv = (const float*)d_in[4];
  const float* Wo   = (const float*)d_in[5];
  const float* bo   = (const float*)d_in[6];
  const float* W1   = (const float*)d_in[7];
  const float* b1   = (const float*)d_in[8];
  const float* W2   = (const float*)d_in[9];
  const float* b2   = (const float*)d_in[10];
  const float* g1   = (const float*)d_in[11];
  const float* be1  = (const float*)d_in[12];
  const float* g2   = (const float*)d_in[13];
  const float* be2  = (const float*)d_in[14];
  const float* tag  = (const float*)d_in[15];
  const float* rw1  = (const float*)d_in[16];
  const float* rb1  = (const float*)d_in[17];
  const float* rw2  = (const float*)d_in[18];
  const float* rb2  = (const float*)d_in[19];
  const float* lmw  = (const float*)d_in[20];
  const float* lmb  = (const float*)d_in[21];
  float* out = (float*)d_out;

  float* ws = (float*)d_ws;
  size_t o = 0;
  float* rep = ws + o;  o += (size_t)NB * NS * ND;           // fp32
  float* x1  = ws + o;  o += (size_t)NB * NS * ND;
  float* partk = ws + o; o += (size_t)4 * NB * NS * ND;       // split-K partials
  float* partial = ws + o; o += (size_t)NB * 32 * ND;         // summary partials (32 groups)
  int* visits = (int*)(ws + o); o += 1024;
  int* active0 = visits + NB * NE;
  int* active1 = active0 + NB;
  int* idx = active1 + NB;
  int* go = idx + NB;
  float* entp = (float*)(go + NB);

  unsigned short* us = (unsigned short*)(ws + o);
  size_t uo = 0;
  unsigned short* rep_b = us + uo; uo += (size_t)NB * NS * ND;
  unsigned short* x1_b  = us + uo; uo += (size_t)NB * NS * ND;
  unsigned short* ctx_b = us + uo; uo += (size_t)NB * NS * ND;
  unsigned short* Qb    = us + uo; uo += (size_t)NB * NS * ND;
  unsigned short* Kb    = us + uo; uo += (size_t)NB * NS * ND;
  unsigned short* Vt    = us + uo; uo += (size_t)NB * NS * ND;
  unsigned short* hid_b = us + uo; uo += (size_t)NB * NS * NFF;
  unsigned short* Wqkv_b = us + uo; uo += (size_t)NE * 3 * ND * ND;
  unsigned short* Wo_b   = us + uo; uo += (size_t)NE * ND * ND;
  unsigned short* W1_b   = us + uo; uo += (size_t)NE * NFF * ND;
  unsigned short* W2_b   = us + uo; uo += (size_t)NE * ND * NFF;
  unsigned short* lmw_b  = us + uo; uo += (size_t)NV * ND;

  // fused weight pre-casts + state init + embedding (deterministic every call)
  {
    int n0 = NE * 3 * ND * ND / 8, n1 = NE * ND * ND / 8, n2 = NE * NFF * ND / 8,
        n3 = NE * ND * NFF / 8, n4 = NV * ND / 8;
    int nbcast = (n0 + n1 + n2 + n3 + n4) / 256;
    k_cast5e<<<nbcast + 16 * NB, 256, 0, stream>>>(
        Wqkv, Wqkv_b, n0, Wo, Wo_b, n1, W1, W1_b, n2, W2, W2_b, n3, lmw, lmw_b, n4,
        nbcast, ids, emb, pe, rep, rep_b, partial, visits, active0, entp);
  }

  for (int step = 0; step < 4; ++step) {
    int* act_in  = (step & 1) ? active1 : active0;
    int* act_out = (step & 1) ? active0 : active1;
    k_router8<<<NB, 256, 0, stream>>>(partial, rw1, rb1, rw2, rb2,
                                      visits, act_in, act_out, idx, go, entp);
    // qkv: rep_b @ Wqkv^T + bqkv -> Qb/Kb bf16, Vt transposed (768 blocks)
    k_gemm64p<2, 0, 1><<<dim3(4, 24, NB), 256, 0, stream>>>(
        rep_b, NS * ND, Wqkv_b, bqkv, nullptr, nullptr, 0, 3 * ND, ND,
        Qb, Kb, Vt, go, idx);
    // attention (staged K/V, P overlay)
    k_attn2<<<dim3(4, NH, NB), 256, 0, stream>>>(Qb, Kb, Vt, ctx_b, go);
    // wo: ctx @ Wo^T -> 2-way split-K partials (512 blocks)
    k_gemm64p<0, 0, 2><<<dim3(8, 8, NB), 256, 0, stream>>>(
        ctx_b, NS * ND, Wo_b, nullptr, partk, nullptr, 0, ND, ND,
        nullptr, nullptr, nullptr, go, idx);
    // x1 = LN(rep + sum(partials) + bo)   (256 blocks)
    k_ln_red<2, 0, 0><<<dim3(32, NB), 256, 0, stream>>>(
        rep, partk, bo, g1, be1, nullptr, x1, x1_b, nullptr, go, idx);
    // hid = relu(x1 @ W1^T + b1) -> bf16 (1024 blocks)
    k_gemm64p<1, 1, 1><<<dim3(4, 32, NB), 256, 0, stream>>>(
        x1_b, NS * ND, W1_b, b1, nullptr, hid_b, NS * NFF, NFF, ND,
        nullptr, nullptr, nullptr, go, idx);
    // w2: hid @ W2^T -> 4-way split-K partials (1024 blocks)
    k_gemm64p<0, 0, 4><<<dim3(16, 8, NB), 256, 0, stream>>>(
        hid_b, NS * NFF, W2_b, nullptr, partk, nullptr, 0, ND, NFF,
        nullptr, nullptr, nullptr, go, idx);
    // rep = LN(x1 + sum(partials) + b2) + tag, + 32-group summary partials (256 blocks)
    k_ln_red<4, 1, 1><<<dim3(32, NB), 256, 0, stream>>>(
        x1, partk, b2, g2, be2, tag, rep, rep_b, partial, go, idx);
  }

  k_lmhead256<<<1000, 512, 0, stream>>>(rep_b, lmw_b, lmb, out, entp);
}

// Round 15
// 505.212 us; speedup vs baseline: 1.1785x; 1.0036x over previous
//
#include <hip/hip_runtime.h>
#include <hip/hip_bf16.h>

#define NB 8
#define NS 256
#define ND 512
#define NH 8
#define NDH 64
#define NFF 2048
#define NE 8
#define NV 32000
#define NRH 256
#define MAXV 2
#define NEGV (-1e9f)

typedef __attribute__((ext_vector_type(8))) short short8;
typedef __attribute__((ext_vector_type(4))) float f32x4;

__device__ __forceinline__ unsigned short f2bf(float x) {
  unsigned int u = __float_as_uint(x);
  u = (u + 0x7fffu + ((u >> 16) & 1u)) >> 16;
  return (unsigned short)u;
}
__device__ __forceinline__ float bf2f(unsigned short x) {
  return __uint_as_float(((unsigned int)x) << 16);
}

// async global->LDS, 16 bytes per lane; LDS dest is wave-uniform base + lane*16
__device__ __forceinline__ void gload16(const unsigned short* g, unsigned short* l) {
  __builtin_amdgcn_global_load_lds(
      (const __attribute__((address_space(1))) unsigned int*)g,
      (__attribute__((address_space(3))) unsigned int*)l, 16, 0, 0);
}

// 32-col-row staging swizzle (lmhead): lane -> chunk (l&3) ^ ((l>>3)&3)
__device__ __forceinline__ int swzc(int lane) {
  return (lane & 3) ^ ((lane >> 3) & 3);
}

// ---------------- fused: weight casts + state init + embedding ----------------
__device__ __forceinline__ void cast8(const float* s, unsigned short* d, int j) {
  const float4* s4 = (const float4*)s;
  float4 a = s4[j * 2], b = s4[j * 2 + 1];
  short8 v;
  v[0] = (short)f2bf(a.x); v[1] = (short)f2bf(a.y);
  v[2] = (short)f2bf(a.z); v[3] = (short)f2bf(a.w);
  v[4] = (short)f2bf(b.x); v[5] = (short)f2bf(b.y);
  v[6] = (short)f2bf(b.z); v[7] = (short)f2bf(b.w);
  *(short8*)&d[(size_t)j * 8] = v;
}

__global__ __launch_bounds__(256) void k_cast5e(
    const float* s0, unsigned short* d0, int n0,
    const float* s1, unsigned short* d1, int n1,
    const float* s2, unsigned short* d2, int n2,
    const float* s3, unsigned short* d3, int n3,
    const float* s4, unsigned short* d4, int n4,
    int nbcast,
    const int* __restrict__ ids, const float* __restrict__ emb,
    const float* __restrict__ pe,
    unsigned short* __restrict__ repb, float* __restrict__ partial,
    int* visits, int* active, float* entp) {
  if (blockIdx.x == 0) {
    if (threadIdx.x < NB * NE) visits[threadIdx.x] = 0;
    if (threadIdx.x < NB) active[threadIdx.x] = 1;
    if (threadIdx.x == 0) *entp = 0.f;
  }
  if ((int)blockIdx.x >= nbcast) {
    int j2 = blockIdx.x - nbcast;
    int rg = j2 & 15, b = j2 >> 4;
    int t = threadIdx.x;
    int c0 = t, c1 = t + 256;
    float pa0 = 0.f, pa1 = 0.f, pb0 = 0.f, pb1 = 0.f;
    for (int row = 0; row < 16; ++row) {
      int s = rg * 16 + row;
      int id = ids[b * NS + s];
      float sc = (id != 0) ? 22.627416997969522f : 0.f;  // sqrt(512), pad row zeroed
      float v0 = emb[(size_t)id * ND + c0] * sc + pe[(size_t)s * ND + c0];
      float v1 = emb[(size_t)id * ND + c1] * sc + pe[(size_t)s * ND + c1];
      size_t base = ((size_t)b * NS + s) * ND;
      repb[base + c0] = f2bf(v0); repb[base + c1] = f2bf(v1);
      if (row < 8) { pa0 += v0; pa1 += v1; } else { pb0 += v0; pb1 += v1; }
    }
    float* ppa = partial + ((size_t)b * 32 + rg * 2) * ND;
    float* ppb = ppa + ND;
    ppa[c0] = pa0; ppa[c1] = pa1;
    ppb[c0] = pb0; ppb[c1] = pb1;
    return;
  }
  int j = blockIdx.x * 256 + threadIdx.x;
  if (j < n0) { cast8(s0, d0, j); return; }
  j -= n0;
  if (j < n1) { cast8(s1, d1, j); return; }
  j -= n1;
  if (j < n2) { cast8(s2, d2, j); return; }
  j -= n2;
  if (j < n3) { cast8(s3, d3, j); return; }
  j -= n3;
  if (j < n4) cast8(s4, d4, j);
}

// ---------------- router: one block per batch; active ping-pong; ent via atomicAdd ----------------
__global__ __launch_bounds__(256) void k_router8(
    const float* __restrict__ partial,
    const float* __restrict__ rw1, const float* __restrict__ rb1,
    const float* __restrict__ rw2, const float* __restrict__ rb2,
    int* visits, const int* __restrict__ active_in, int* active_out,
    int* idx, int* go, float* ent_total) {
  int b = blockIdx.x;
  __shared__ float sm[ND];
  __shared__ float h[NRH];
  __shared__ float lg[NE + 1];
  __shared__ int scnt;
  int t = threadIdx.x;
  for (int i = t; i < ND; i += 256) {
    const float* pp = partial + ((size_t)b * 32) * ND + i;
    float s = 0.f;
#pragma unroll
    for (int rg = 0; rg < 32; ++rg) s += pp[(size_t)rg * ND];
    sm[i] = s * (1.f / NS);
  }
  if (t == 0) {
    int c = 0;
    for (int bb = 0; bb < NB; ++bb) c += active_in[bb];
    scnt = c;
  }
  __syncthreads();
  {
    const float* w = rw1 + (size_t)t * ND;
    float acc = rb1[t];
    for (int d = 0; d < ND; ++d) acc += sm[d] * w[d];
    h[t] = fmaxf(acc, 0.f);
  }
  __syncthreads();
  if (t < NE + 1) {
    const float* w = rw2 + t * NRH;
    float a = rb2[t];
    for (int r = 0; r < NRH; ++r) a += h[r] * w[r];
    lg[t] = a;
  }
  __syncthreads();
  if (t == 0) {
    int aprev = active_in[b];
    float l[NE + 1];
    for (int e = 0; e < NE; ++e)
      l[e] = (visits[b * NE + e] >= MAXV) ? NEGV : lg[e];
    l[NE] = lg[NE];
    float m = l[0];
    for (int e = 1; e <= NE; ++e) m = fmaxf(m, l[e]);
    float z = 0.f, p[NE + 1];
    for (int e = 0; e <= NE; ++e) { p[e] = __expf(l[e] - m); z += p[e]; }
    float zi = 1.f / z, ent = 0.f;
    for (int e = 0; e <= NE; ++e) {
      float pp = p[e] * zi;
      ent -= pp * __logf(pp + 1e-9f);
    }
    if (aprev && scnt > 0) atomicAdd(ent_total, ent / (float)scnt);
    int ch = 0; float bm = l[0];
    for (int e = 1; e <= NE; ++e) if (l[e] > bm) { bm = l[e]; ch = e; }
    int g = (aprev && ch < NE) ? 1 : 0;
    int ix = g ? ch : 0;
    visits[b * NE + ix] += g;
    idx[b] = ix; go[b] = g; active_out[b] = g;
  }
}

// ---------------- 64x64-tile bf16 MFMA expert GEMM, BK=64, depth-2 counted-vmcnt ----------------
// OUT: 0 = fp32 split-K partials (no bias), 1 = bf16 + bias (+relu), 2 = qkv-split.
// SK = split-K ways. grid (4*SK, N/64, NB). Fully gated.
template <int OUT, int RELU, int SK>
__global__ __launch_bounds__(256) void k_gemm64p(
    const unsigned short* __restrict__ Aall, int sa,
    const unsigned short* __restrict__ Wall, const float* __restrict__ ball,
    float* __restrict__ Pall, unsigned short* __restrict__ Uall, int so,
    int N, int K,
    unsigned short* __restrict__ Qb, unsigned short* __restrict__ Kb,
    unsigned short* __restrict__ Vt,
    const int* __restrict__ go, const int* __restrict__ idx) {
  int b = blockIdx.z;
  if (!go[b]) return;
  int t = threadIdx.x;
  int lane = t & 63, w = t >> 6;
  int wm = (w >> 1) * 32, wn = (w & 1) * 32;
  int kc = blockIdx.x >> 2;
  int bm = (blockIdx.x & 3) * 64, bn = blockIdx.y * 64;
  int KC = K / SK;
  int lrow = (lane >> 4) * 4, lcol = lane & 15;
  const unsigned short* A = Aall + (size_t)b * sa + kc * KC;
  const unsigned short* W = Wall + (size_t)idx[b] * N * K + kc * KC;

  __shared__ __align__(16) unsigned short As[2][64][64];  // 16 KB
  __shared__ __align__(16) unsigned short Bs[2][64][64];  // 16 KB
  f32x4 acc[2][2];
#pragma unroll
  for (int i = 0; i < 2; ++i)
#pragma unroll
    for (int j = 0; j < 2; ++j) acc[i][j] = (f32x4){0.f, 0.f, 0.f, 0.f};

  // wave w stages rows [w*16, w*16+16); lane l -> row (l>>3), chunk (l&7)^((l>>3)&7)
  int ch8 = (lane & 7) ^ ((lane >> 3) & 7);
  const unsigned short* ga = A + (size_t)(bm + w * 16 + (lane >> 3)) * K + ch8 * 8;
  const unsigned short* gb = W + (size_t)(bn + w * 16 + (lane >> 3)) * K + ch8 * 8;

#define ISSUE64(slot, kt)                                            \
  gload16(ga + (size_t)(kt) * 64, &As[slot][w * 16][0]);             \
  gload16(ga + (size_t)(kt) * 64 + 8 * (size_t)K, &As[slot][w * 16 + 8][0]); \
  gload16(gb + (size_t)(kt) * 64, &Bs[slot][w * 16][0]);             \
  gload16(gb + (size_t)(kt) * 64 + 8 * (size_t)K, &Bs[slot][w * 16 + 8][0]);

  int nk = KC >> 6;  // >= 4 for all uses
  ISSUE64(0, 0)
  ISSUE64(1, 1)

  int row0 = lane & 15, g = lane >> 4;
  for (int it = 0; it < nk; ++it) {
    if (it < nk - 1) asm volatile("s_waitcnt vmcnt(4)" ::: "memory");
    else             asm volatile("s_waitcnt vmcnt(0)" ::: "memory");
    asm volatile("s_barrier" ::: "memory");  // all waves: tile it landed
    int sl = it & 1;
    __builtin_amdgcn_s_setprio(1);
#pragma unroll
    for (int kk = 0; kk < 2; ++kk) {
      int co = ((kk * 4 + g) ^ (row0 & 7)) * 8;
      short8 a0 = *(const short8*)&As[sl][wm + row0][co];
      short8 a1 = *(const short8*)&As[sl][wm + 16 + row0][co];
      short8 b0 = *(const short8*)&Bs[sl][wn + row0][co];
      short8 b1 = *(const short8*)&Bs[sl][wn + 16 + row0][co];
      acc[0][0] = __builtin_amdgcn_mfma_f32_16x16x32_bf16(a0, b0, acc[0][0], 0, 0, 0);
      acc[0][1] = __builtin_amdgcn_mfma_f32_16x16x32_bf16(a0, b1, acc[0][1], 0, 0, 0);
      acc[1][0] = __builtin_amdgcn_mfma_f32_16x16x32_bf16(a1, b0, acc[1][0], 0, 0, 0);
      acc[1][1] = __builtin_amdgcn_mfma_f32_16x16x32_bf16(a1, b1, acc[1][1], 0, 0, 0);
    }
    __builtin_amdgcn_s_setprio(0);
    asm volatile("s_barrier" ::: "memory");  // all waves done reading slot sl
    if (it + 2 < nk) { ISSUE64(sl, it + 2) }
  }
#undef ISSUE64

  if (OUT == 2) {
    const float* bias = ball + (size_t)idx[b] * N;
    int seg = bn >> 9;  // 0:Q 1:K 2:V — 64-tile never crosses a 512 boundary
#pragma unroll
    for (int nf = 0; nf < 2; ++nf) {
      int col = bn + wn + nf * 16 + lcol;
      float bv = bias[col];
      if (seg < 2) {
        unsigned short* dst = (seg == 0) ? Qb : Kb;
        int cc = col - seg * 512;
#pragma unroll
        for (int mf = 0; mf < 2; ++mf)
#pragma unroll
          for (int r = 0; r < 4; ++r) {
            int row = bm + wm + mf * 16 + lrow + r;
            dst[((size_t)b * NS + row) * ND + cc] = f2bf(acc[mf][nf][r] + bv);
          }
      } else {
        int dcol = col - 1024;
#pragma unroll
        for (int mf = 0; mf < 2; ++mf) {
          int s0 = bm + wm + mf * 16 + lrow;
          unsigned long long pk =
              (unsigned long long)f2bf(acc[mf][nf][0] + bv) |
              ((unsigned long long)f2bf(acc[mf][nf][1] + bv) << 16) |
              ((unsigned long long)f2bf(acc[mf][nf][2] + bv) << 32) |
              ((unsigned long long)f2bf(acc[mf][nf][3] + bv) << 48);
          *(unsigned long long*)&Vt[((size_t)b * 512 + dcol) * 256 + s0] = pk;
        }
      }
    }
  } else if (OUT == 1) {
    const float* bias = ball + (size_t)idx[b] * N;
#pragma unroll
    for (int nf = 0; nf < 2; ++nf) {
      int col = bn + wn + nf * 16 + lcol;
      float bv = bias[col];
#pragma unroll
      for (int mf = 0; mf < 2; ++mf) {
#pragma unroll
        for (int r = 0; r < 4; ++r) {
          int row = bm + wm + mf * 16 + lrow + r;
          float v = acc[mf][nf][r] + bv;
          if (RELU) v = fmaxf(v, 0.f);
          Uall[(size_t)b * so + (size_t)row * N + col] = f2bf(v);
        }
      }
    }
  } else {
    float* P = Pall + ((size_t)kc * NB + b) * ((size_t)NS * N);
#pragma unroll
    for (int nf = 0; nf < 2; ++nf) {
      int col = bn + wn + nf * 16 + lcol;
#pragma unroll
      for (int mf = 0; mf < 2; ++mf)
#pragma unroll
        for (int r = 0; r < 4; ++r)
          P[(size_t)(bm + wm + mf * 16 + lrow + r) * N + col] = acc[mf][nf][r];
    }
  }
}

// ---------------- MFMA flash attention, staged K (P overlay), V direct ----------------
__global__ __launch_bounds__(256) void k_attn2(const unsigned short* __restrict__ Qb,
                                               const unsigned short* __restrict__ Kb,
                                               const unsigned short* __restrict__ Vt,
                                               unsigned short* __restrict__ ctxb,
                                               const int* __restrict__ go) {
  int b = blockIdx.z, h = blockIdx.y, qt = blockIdx.x;
  if (!go[b]) return;  // ctx_b consumers are gated
  int t = threadIdx.x;
  __shared__ __align__(16) unsigned short lds0[16384];  // K then P (32 KB)
  int lane = t & 63, w = t >> 6, g = lane >> 4, c = lane & 15;

  // stage K: rows k=0..255, 64 d; swizzled
#pragma unroll
  for (int i = 0; i < 8; ++i) {
    int task = i * 256 + t;
    int k = task >> 3, cc = task & 7;
    short8 v = *(const short8*)&Kb[((size_t)b * NS + k) * ND + h * NDH + cc * 8];
    *(short8*)&lds0[k * 64 + ((cc * 8) ^ ((k & 7) << 3))] = v;
  }
  short8 qf[2];
  {
    const unsigned short* qp = Qb + ((size_t)b * NS + qt * 64 + w * 16 + c) * ND + h * NDH;
    qf[0] = *(const short8*)&qp[g * 8];
    qf[1] = *(const short8*)&qp[32 + g * 8];
  }
  __syncthreads();

  f32x4 sacc[16];
#pragma unroll
  for (int mf = 0; mf < 16; ++mf) sacc[mf] = (f32x4){0.f, 0.f, 0.f, 0.f};
#pragma unroll
  for (int mf = 0; mf < 16; ++mf) {
#pragma unroll
    for (int kd = 0; kd < 2; ++kd) {
      int row = mf * 16 + c;
      short8 kf = *(const short8*)&lds0[row * 64 + ((kd * 32 + g * 8) ^ ((row & 7) << 3))];
      sacc[mf] = __builtin_amdgcn_mfma_f32_16x16x32_bf16(kf, qf[kd], sacc[mf], 0, 0, 0);
    }
  }
  __syncthreads();  // lds0 becomes P

  float mx = -3.4e38f;
#pragma unroll
  for (int mf = 0; mf < 16; ++mf) {
#pragma unroll
    for (int r = 0; r < 4; ++r) {
      sacc[mf][r] *= 0.125f;
      mx = fmaxf(mx, sacc[mf][r]);
    }
  }
  mx = fmaxf(mx, __shfl_xor(mx, 16));
  mx = fmaxf(mx, __shfl_xor(mx, 32));
  float sum = 0.f;
#pragma unroll
  for (int mf = 0; mf < 16; ++mf)
#pragma unroll
    for (int r = 0; r < 4; ++r) {
      float p = __expf(sacc[mf][r] - mx);
      sacc[mf][r] = p;
      sum += p;
    }
  sum += __shfl_xor(sum, 16);
  sum += __shfl_xor(sum, 32);
  float zi = 1.f / sum;

  int q_l = w * 16 + c;
#pragma unroll
  for (int mf = 0; mf < 16; ++mf) {
    unsigned long long pk =
        (unsigned long long)f2bf(sacc[mf][0] * zi) |
        ((unsigned long long)f2bf(sacc[mf][1] * zi) << 16) |
        ((unsigned long long)f2bf(sacc[mf][2] * zi) << 32) |
        ((unsigned long long)f2bf(sacc[mf][3] * zi) << 48);
    *(unsigned long long*)&lds0[q_l * 256 + ((mf * 16 + g * 4) ^ ((q_l & 7) << 3))] = pk;
  }
  __syncthreads();

  // ctx = P @ V; V^T read directly from global (L2-resident, written this step)
  f32x4 cacc[4];
#pragma unroll
  for (int nf = 0; nf < 4; ++nf) cacc[nf] = (f32x4){0.f, 0.f, 0.f, 0.f};
  const unsigned short* vbase = Vt + ((size_t)b * 512 + h * NDH) * 256;
#pragma unroll
  for (int ks = 0; ks < 8; ++ks) {
    int prow = w * 16 + c;
    short8 pf = *(const short8*)&lds0[prow * 256 + ((ks * 32 + g * 8) ^ ((prow & 7) << 3))];
#pragma unroll
    for (int nf = 0; nf < 4; ++nf) {
      short8 vf = *(const short8*)&vbase[(size_t)(nf * 16 + c) * 256 + ks * 32 + g * 8];
      cacc[nf] = __builtin_amdgcn_mfma_f32_16x16x32_bf16(pf, vf, cacc[nf], 0, 0, 0);
    }
  }
#pragma unroll
  for (int nf = 0; nf < 4; ++nf)
#pragma unroll
    for (int r = 0; r < 4; ++r)
      ctxb[((size_t)b * NS + qt * 64 + w * 16 + g * 4 + r) * ND + h * NDH + nf * 16 + c] =
          f2bf(cacc[nf][r]);
}

// ---------------- partial-reduce + GEMM bias + bf16 residual + LayerNorm (+tag, +summary) ----------------
// 8 rows/block, grid (32, NB). Gated. part = [NCH][NB][NS][ND] fp32 split-K partials.
template <int NCH, int TAG, int SUMP>
__global__ __launch_bounds__(256) void k_ln_red(
    const unsigned short* __restrict__ resb, const float* __restrict__ part,
    const float* __restrict__ gbias,
    const float* __restrict__ gall, const float* __restrict__ beall,
    const float* __restrict__ tagall,
    unsigned short* __restrict__ outb,
    float* __restrict__ sump,
    const int* __restrict__ go, const int* __restrict__ idx) {
  int b = blockIdx.y;
  if (!go[b]) return;
  int rg = blockIdx.x;  // 0..31, 8 rows each
  int w = threadIdx.x >> 6, l = threadIdx.x & 63;
  int ix = idx[b];
  int d = l * 8;
  float gb8[8], gg[8], bb[8];
  {
    float4 a0 = *(const float4*)&gbias[ix * ND + d];
    float4 a1 = *(const float4*)&gbias[ix * ND + d + 4];
    gb8[0] = a0.x; gb8[1] = a0.y; gb8[2] = a0.z; gb8[3] = a0.w;
    gb8[4] = a1.x; gb8[5] = a1.y; gb8[6] = a1.z; gb8[7] = a1.w;
    float4 g0 = *(const float4*)&gall[ix * ND + d];
    float4 g1 = *(const float4*)&gall[ix * ND + d + 4];
    gg[0] = g0.x; gg[1] = g0.y; gg[2] = g0.z; gg[3] = g0.w;
    gg[4] = g1.x; gg[5] = g1.y; gg[6] = g1.z; gg[7] = g1.w;
    float4 b0 = *(const float4*)&beall[ix * ND + d];
    float4 b1 = *(const float4*)&beall[ix * ND + d + 4];
    bb[0] = b0.x; bb[1] = b0.y; bb[2] = b0.z; bb[3] = b0.w;
    bb[4] = b1.x; bb[5] = b1.y; bb[6] = b1.z; bb[7] = b1.w;
    if (TAG) {
      float4 t0 = *(const float4*)&tagall[ix * ND + d];
      float4 t1 = *(const float4*)&tagall[ix * ND + d + 4];
      bb[0] += t0.x; bb[1] += t0.y; bb[2] += t0.z; bb[3] += t0.w;
      bb[4] += t1.x; bb[5] += t1.y; bb[6] += t1.z; bb[7] += t1.w;
    }
  }
  float ps[8] = {0.f, 0.f, 0.f, 0.f, 0.f, 0.f, 0.f, 0.f};
  const size_t CSTRIDE = (size_t)NB * NS * ND;
  for (int rr = 0; rr < 2; ++rr) {
    int s = rg * 8 + w * 2 + rr;
    size_t base = ((size_t)b * NS + s) * ND;
    short8 xr = *(const short8*)&resb[base + d];
    float v[8];
#pragma unroll
    for (int j = 0; j < 8; ++j) v[j] = bf2f((unsigned short)xr[j]) + gb8[j];
#pragma unroll
    for (int c = 0; c < NCH; ++c) {
      const float* pc = part + c * CSTRIDE + base;
      float4 p0 = *(const float4*)&pc[d];
      float4 p1 = *(const float4*)&pc[d + 4];
      v[0] += p0.x; v[1] += p0.y; v[2] += p0.z; v[3] += p0.w;
      v[4] += p1.x; v[5] += p1.y; v[6] += p1.z; v[7] += p1.w;
    }
    float sum = 0.f;
#pragma unroll
    for (int j = 0; j < 8; ++j) sum += v[j];
#pragma unroll
    for (int off = 1; off < 64; off <<= 1) sum += __shfl_xor(sum, off);
    float mu = sum * (1.f / ND);
    float var = 0.f;
#pragma unroll
    for (int j = 0; j < 8; ++j) { v[j] -= mu; var += v[j] * v[j]; }
#pragma unroll
    for (int off = 1; off < 64; off <<= 1) var += __shfl_xor(var, off);
    float rs = rsqrtf(var * (1.f / ND) + 1e-5f);
    float o[8];
    short8 ob;
#pragma unroll
    for (int j = 0; j < 8; ++j) {
      o[j] = v[j] * rs * gg[j] + bb[j];
      if (SUMP) ps[j] += o[j];
      ob[j] = (short)f2bf(o[j]);
    }
    *(short8*)&outb[base + d] = ob;
  }
  if (SUMP) {
    __shared__ float pl[4][ND];
#pragma unroll
    for (int j = 0; j < 8; ++j) pl[w][d + j] = ps[j];
    __syncthreads();
    if (w == 0) {
      float* pp = sump + ((size_t)b * 32 + rg) * ND;
#pragma unroll
      for (int j = 0; j < 8; ++j)
        pp[d + j] = pl[0][d + j] + pl[1][d + j] + pl[2][d + j] + pl[3][d + j];
    }
  }
}

// ---------------- LM head: 256x256-tile bf16 MFMA GEMM, 8 waves, counted-vmcnt depth-2 ----------------
__global__ __launch_bounds__(512, 2) void k_lmhead256(const unsigned short* __restrict__ Ab,
                                                      const unsigned short* __restrict__ Wb,
                                                      const float* __restrict__ bias,
                                                      float* __restrict__ out,
                                                      const float* __restrict__ entp) {
  if (blockIdx.x == 0 && threadIdx.x == 0)
    out[(size_t)NB * NS * NV] = *entp;  // fused k_ent
  int id = blockIdx.x;
  int swz = (id & 7) * 125 + (id >> 3);  // bijective: 1000 = 8 * 125
  int bm = (swz % 8) * 256;
  int bn = (swz / 8) * 256;

  __shared__ __align__(16) unsigned short As[2][256][32];
  __shared__ __align__(16) unsigned short Bs[2][256][32];
  int t = threadIdx.x;
  int lane = t & 63, w = t >> 6;
  int wm = (w >> 2) * 128, wn = (w & 3) * 64;
  f32x4 acc[8][4];
#pragma unroll
  for (int i = 0; i < 8; ++i)
#pragma unroll
    for (int j = 0; j < 4; ++j) acc[i][j] = (f32x4){0.f, 0.f, 0.f, 0.f};

  const unsigned short* ga = Ab + (size_t)(bm + w * 32 + (lane >> 2)) * ND + swzc(lane) * 8;
  const unsigned short* gb = Wb + (size_t)(bn + w * 32 + (lane >> 2)) * ND + swzc(lane) * 8;

#define ISSUEL(slot, kt)                                           \
  gload16(ga + (kt) * 32, &As[slot][w * 32][0]);                   \
  gload16(ga + (kt) * 32 + 16 * ND, &As[slot][w * 32 + 16][0]);    \
  gload16(gb + (kt) * 32, &Bs[slot][w * 32][0]);                   \
  gload16(gb + (kt) * 32 + 16 * ND, &Bs[slot][w * 32 + 16][0]);

  ISSUEL(0, 0)
  ISSUEL(1, 1)

  int row0 = lane & 15;
  int cs = ((lane >> 4) ^ ((row0 >> 1) & 3)) * 8;
  for (int it = 0; it < 16; ++it) {
    if (it < 15) asm volatile("s_waitcnt vmcnt(4)" ::: "memory");
    else         asm volatile("s_waitcnt vmcnt(0)" ::: "memory");
    asm volatile("s_barrier" ::: "memory");  // tile it landed for all waves
    int sl = it & 1;
    short8 a[8], bfr[4];
#pragma unroll
    for (int mf = 0; mf < 8; ++mf)
      a[mf] = *(const short8*)&As[sl][wm + mf * 16 + row0][cs];
#pragma unroll
    for (int nf = 0; nf < 4; ++nf)
      bfr[nf] = *(const short8*)&Bs[sl][wn + nf * 16 + row0][cs];
    __builtin_amdgcn_s_setprio(1);
#pragma unroll
    for (int mf = 0; mf < 8; ++mf)
#pragma unroll
      for (int nf = 0; nf < 4; ++nf)
        acc[mf][nf] = __builtin_amdgcn_mfma_f32_16x16x32_bf16(a[mf], bfr[nf], acc[mf][nf], 0, 0, 0);
    __builtin_amdgcn_s_setprio(0);
    asm volatile("s_barrier" ::: "memory");  // reads of slot sl done
    if (it + 2 < 16) { ISSUEL(sl, it + 2) }
  }
#undef ISSUEL

  int lrow = (lane >> 4) * 4, lcol = lane & 15;
#pragma unroll
  for (int nf = 0; nf < 4; ++nf) {
    int col = bn + wn + nf * 16 + lcol;
    float bv = bias[col];
#pragma unroll
    for (int mf = 0; mf < 8; ++mf) {
#pragma unroll
      for (int r = 0; r < 4; ++r) {
        int row = bm + wm + mf * 16 + lrow + r;
        out[(size_t)row * NV + col] = acc[mf][nf][r] + bv;
      }
    }
  }
}

extern "C" void kernel_launch(void* const* d_in, const int* in_sizes, int n_in,
                              void* d_out, int out_size, void* d_ws, size_t ws_size,
                              hipStream_t stream) {
  const int* ids   = (const int*)d_in[0];
  const float* emb = (const float*)d_in[1];
  const float* pe  = (const float*)d_in[2];
  const float* Wqkv = (const float*)d_in[3];
  const float* bqkv = (const float*)d_in[4];
  const float* Wo   = (const float*)d_in[5];
  const float* bo   = (const float*)d_in[6];
  const float* W1   = (const float*)d_in[7];
  const float* b1   = (const float*)d_in[8];
  const float* W2   = (const float*)d_in[9];
  const float* b2   = (const float*)d_in[10];
  const float* g1   = (const float*)d_in[11];
  const float* be1  = (const float*)d_in[12];
  const float* g2   = (const float*)d_in[13];
  const float* be2  = (const float*)d_in[14];
  const float* tag  = (const float*)d_in[15];
  const float* rw1  = (const float*)d_in[16];
  const float* rb1  = (const float*)d_in[17];
  const float* rw2  = (const float*)d_in[18];
  const float* rb2  = (const float*)d_in[19];
  const float* lmw  = (const float*)d_in[20];
  const float* lmb  = (const float*)d_in[21];
  float* out = (float*)d_out;

  float* ws = (float*)d_ws;
  size_t o = 0;
  float* partk = ws + o; o += (size_t)4 * NB * NS * ND;       // split-K partials
  float* partial = ws + o; o += (size_t)NB * 32 * ND;         // summary partials (32 groups)
  int* visits = (int*)(ws + o); o += 1024;
  int* active0 = visits + NB * NE;
  int* active1 = active0 + NB;
  int* idx = active1 + NB;
  int* go = idx + NB;
  float* entp = (float*)(go + NB);

  unsigned short* us = (unsigned short*)(ws + o);
  size_t uo = 0;
  unsigned short* rep_b = us + uo; uo += (size_t)NB * NS * ND;
  unsigned short* x1_b  = us + uo; uo += (size_t)NB * NS * ND;
  unsigned short* ctx_b = us + uo; uo += (size_t)NB * NS * ND;
  unsigned short* Qb    = us + uo; uo += (size_t)NB * NS * ND;
  unsigned short* Kb    = us + uo; uo += (size_t)NB * NS * ND;
  unsigned short* Vt    = us + uo; uo += (size_t)NB * NS * ND;
  unsigned short* hid_b = us + uo; uo += (size_t)NB * NS * NFF;
  unsigned short* Wqkv_b = us + uo; uo += (size_t)NE * 3 * ND * ND;
  unsigned short* Wo_b   = us + uo; uo += (size_t)NE * ND * ND;
  unsigned short* W1_b   = us + uo; uo += (size_t)NE * NFF * ND;
  unsigned short* W2_b   = us + uo; uo += (size_t)NE * ND * NFF;
  unsigned short* lmw_b  = us + uo; uo += (size_t)NV * ND;

  // fused weight pre-casts + state init + embedding (deterministic every call)
  {
    int n0 = NE * 3 * ND * ND / 8, n1 = NE * ND * ND / 8, n2 = NE * NFF * ND / 8,
        n3 = NE * ND * NFF / 8, n4 = NV * ND / 8;
    int nbcast = (n0 + n1 + n2 + n3 + n4) / 256;
    k_cast5e<<<nbcast + 16 * NB, 256, 0, stream>>>(
        Wqkv, Wqkv_b, n0, Wo, Wo_b, n1, W1, W1_b, n2, W2, W2_b, n3, lmw, lmw_b, n4,
        nbcast, ids, emb, pe, rep_b, partial, visits, active0, entp);
  }

  for (int step = 0; step < 4; ++step) {
    int* act_in  = (step & 1) ? active1 : active0;
    int* act_out = (step & 1) ? active0 : active1;
    k_router8<<<NB, 256, 0, stream>>>(partial, rw1, rb1, rw2, rb2,
                                      visits, act_in, act_out, idx, go, entp);
    // qkv: rep_b @ Wqkv^T + bqkv -> Qb/Kb bf16, Vt transposed (768 blocks)
    k_gemm64p<2, 0, 1><<<dim3(4, 24, NB), 256, 0, stream>>>(
        rep_b, NS * ND, Wqkv_b, bqkv, nullptr, nullptr, 0, 3 * ND, ND,
        Qb, Kb, Vt, go, idx);
    // attention (staged K, V direct)
    k_attn2<<<dim3(4, NH, NB), 256, 0, stream>>>(Qb, Kb, Vt, ctx_b, go);
    // wo: ctx @ Wo^T -> 2-way split-K partials (512 blocks)
    k_gemm64p<0, 0, 2><<<dim3(8, 8, NB), 256, 0, stream>>>(
        ctx_b, NS * ND, Wo_b, nullptr, partk, nullptr, 0, ND, ND,
        nullptr, nullptr, nullptr, go, idx);
    // x1 = LN(rep + sum(partials) + bo)   (256 blocks)
    k_ln_red<2, 0, 0><<<dim3(32, NB), 256, 0, stream>>>(
        rep_b, partk, bo, g1, be1, nullptr, x1_b, nullptr, go, idx);
    // hid = relu(x1 @ W1^T + b1) -> bf16 (1024 blocks)
    k_gemm64p<1, 1, 1><<<dim3(4, 32, NB), 256, 0, stream>>>(
        x1_b, NS * ND, W1_b, b1, nullptr, hid_b, NS * NFF, NFF, ND,
        nullptr, nullptr, nullptr, go, idx);
    // w2: hid @ W2^T -> 4-way split-K partials (1024 blocks)
    k_gemm64p<0, 0, 4><<<dim3(16, 8, NB), 256, 0, stream>>>(
        hid_b, NS * NFF, W2_b, nullptr, partk, nullptr, 0, ND, NFF,
        nullptr, nullptr, nullptr, go, idx);
    // rep = LN(x1 + sum(partials) + b2) + tag, + 32-group summary partials (256 blocks)
    k_ln_red<4, 1, 1><<<dim3(32, NB), 256, 0, stream>>>(
        x1_b, partk, b2, g2, be2, tag, rep_b, partial, go, idx);
  }

  k_lmhead256<<<1000, 512, 0, stream>>>(rep_b, lmw_b, lmb, out, entp);
}